// Round 9
// baseline (247.186 us; speedup 1.0000x reference)
//
#include <hip/hip_runtime.h>
#include <hip/hip_bf16.h>
#include <stdint.h>

typedef unsigned short u16;
typedef short bf16x8 __attribute__((ext_vector_type(8)));
typedef float f32x4 __attribute__((ext_vector_type(4)));

#define C_IN 768
#define AHS 384
#define NH 6
#define HD 64
#define KK9 9
#define BSEQ 2048
#define MTOT 8192

__device__ __forceinline__ float b2f(u16 u){
  union { unsigned u; float f; } v; v.u = ((unsigned)u) << 16; return v.f;
}
__device__ __forceinline__ u16 f2b(float f){
  union { float f; unsigned u; } v; v.f = f;
  unsigned r = (v.u + 0x7FFFu + ((v.u >> 16) & 1u)) >> 16;
  return (u16)r;
}
__device__ __forceinline__ void gload_lds16(const void* g, void* l){
  __builtin_amdgcn_global_load_lds((const __attribute__((address_space(1))) unsigned int*)g,
                                   (__attribute__((address_space(3))) unsigned int*)l, 16, 0, 0);
}
__device__ __forceinline__ unsigned cvtpk_bf16(float lo, float hi){
  unsigned w;
  asm("v_cvt_pk_bf16_f32 %0, %1, %2" : "=v"(w) : "v"(lo), "v"(hi));
  return w;
}

#define SCL 0.18033688011112042f   // 0.125 * log2(e)
#define INVSCL 5.545177444479562f  // 8 * ln(2)
#define LOG2E 1.4426950408889634f

// ---------------- transpose + cast f32[R][C] -> bf16[C][R], 5 weights fused ----------------
__global__ void k_transpose_cast5(const float* __restrict__ s0, const float* __restrict__ s1,
                                  const float* __restrict__ s2, const float* __restrict__ s3,
                                  const float* __restrict__ s4,
                                  u16* __restrict__ d0, u16* __restrict__ d1, u16* __restrict__ d2,
                                  u16* __restrict__ d3, u16* __restrict__ d4){
  __shared__ float t[32][33];
  int z = blockIdx.z;
  const float* src = (z==0)?s0:(z==1)?s1:(z==2)?s2:(z==3)?s3:s4;
  u16* dst = (z==0)?d0:(z==1)?d1:(z==2)?d2:(z==3)?d3:d4;
  const int R = C_IN, C = AHS;
  int r0 = blockIdx.x*32, c0 = blockIdx.y*32;
  int tx = threadIdx.x, ty = threadIdx.y;
  #pragma unroll
  for (int j=0;j<4;j++){
    int r = r0 + ty + j*8, c = c0 + tx;
    t[ty+j*8][tx] = src[(size_t)r*C + c];
  }
  __syncthreads();
  #pragma unroll
  for (int j=0;j<4;j++){
    int c = c0 + ty + j*8, r = r0 + tx;
    dst[(size_t)c*R + r] = f2b(t[tx][ty+j*8]);
  }
}

__global__ void k_transpose_cast(const float* __restrict__ src, u16* __restrict__ dst, int R, int C){
  __shared__ float t[32][33];
  int r0 = blockIdx.x*32, c0 = blockIdx.y*32;
  int tx = threadIdx.x, ty = threadIdx.y;
  #pragma unroll
  for (int j=0;j<4;j++){
    int r = r0 + ty + j*8, c = c0 + tx;
    t[ty+j*8][tx] = (r<R && c<C) ? src[(size_t)r*C + c] : 0.f;
  }
  __syncthreads();
  #pragma unroll
  for (int j=0;j<4;j++){
    int c = c0 + ty + j*8, r = r0 + tx;
    if (r<R && c<C) dst[(size_t)c*R + r] = f2b(t[tx][ty+j*8]);
  }
}

// ---------------- X cast + depthwise conv (SAME), plus M8 = amask*log2e ----------------
__global__ __launch_bounds__(192) void k_prep_x(const float* __restrict__ X, const float* __restrict__ dwk,
                          const float* __restrict__ amask,
                          u16* __restrict__ Xbf, u16* __restrict__ DWbf, float* __restrict__ M8){
  int blk = blockIdx.x; int b = blk>>11; int s = blk&2047;
  int c0 = threadIdx.x*4;
  if (threadIdx.x == 0) M8[blk] = amask[blk] * LOG2E;
  size_t base = (size_t)blk*C_IN + c0;
  float4 xc = *(const float4*)(X + base);
  *(ushort4*)(Xbf + base) = make_ushort4(f2b(xc.x), f2b(xc.y), f2b(xc.z), f2b(xc.w));
  float a0=0.f,a1=0.f,a2=0.f,a3=0.f;
  #pragma unroll
  for (int k=0;k<KK9;k++){
    int ss = s + k - 4;
    if ((unsigned)ss < 2048u){
      float4 xv = *(const float4*)(X + ((size_t)((b<<11)+ss)*C_IN + c0));
      float4 wv = *(const float4*)(dwk + k*C_IN + c0);
      a0 += xv.x*wv.x; a1 += xv.y*wv.y; a2 += xv.z*wv.z; a3 += xv.w*wv.w;
    }
  }
  *(ushort4*)(DWbf + base) = make_ushort4(f2b(a0), f2b(a1), f2b(a2), f2b(a3));
}

// ---------------- 5-way fused projection GEMM: [8192,768]x[768,384] ----------------
// z: 0=Q(-> scaled by SCL) 1=K 2=V(-> transposed Vt) 3=CO 4=KeyConv
__global__ __launch_bounds__(256) void k_gemm5(
    const u16* __restrict__ Xbf, const u16* __restrict__ DWbf,
    const u16* __restrict__ WtQ, const u16* __restrict__ WtK, const u16* __restrict__ WtV,
    const u16* __restrict__ WtCO, const u16* __restrict__ WtPW,
    const float* __restrict__ bq, const float* __restrict__ bk_, const float* __restrict__ bv,
    const float* __restrict__ bco, const float* __restrict__ bcv,
    u16* __restrict__ Qo, u16* __restrict__ Ko, u16* __restrict__ Vt,
    u16* __restrict__ COo, u16* __restrict__ KCo)
{
  __shared__ char smem[32768];
  int tid = threadIdx.x, l = tid&63, w = tid>>6;
  int g = l>>4, c = l&15;
  int wr = w>>1, wc = w&1;
  int mt = blockIdx.x, nt = blockIdx.y, z = blockIdx.z;
  const u16* A = (z==4) ? DWbf : Xbf;
  const u16* B = (z==0)?WtQ:(z==1)?WtK:(z==2)?WtV:(z==3)?WtCO:WtPW;
  const float* bias = (z==0)?bq:(z==1)?bk_:(z==2)?bv:(z==3)?bco:bcv;
  float oscale = (z==0) ? SCL : 1.0f;

  char* La = smem; char* Lb = smem + 16384;
  int m0 = mt*128, n0 = nt*128;

  f32x4 zero = {0.f,0.f,0.f,0.f};
  f32x4 acc[4][4];
  #pragma unroll
  for (int i=0;i<4;i++)
    #pragma unroll
    for (int j=0;j<4;j++) acc[i][j] = zero;

  int rr = w*8 + (l>>3);
  int ch = l&7;

  for (int kt=0; kt<12; kt++){
    #pragma unroll
    for (int i=0;i<4;i++){
      int row = i*32 + rr;
      int sc = ch ^ (row&7);
      gload_lds16(A + (size_t)(m0+row)*C_IN + kt*64 + sc*8, La + i*4096 + w*1024);
      gload_lds16(B + (size_t)(n0+row)*C_IN + kt*64 + sc*8, Lb + i*4096 + w*1024);
    }
    __syncthreads();
    bf16x8 af[4][2], bfr[4][2];
    #pragma unroll
    for (int mi=0;mi<4;mi++){
      int row = wr*64 + mi*16 + c;
      #pragma unroll
      for (int kk=0;kk<2;kk++){
        int sw = (kk*4+g) ^ (row&7);
        af[mi][kk] = *(const bf16x8*)(La + row*128 + sw*16);
      }
    }
    #pragma unroll
    for (int ni=0;ni<4;ni++){
      int row = wc*64 + ni*16 + c;
      #pragma unroll
      for (int kk=0;kk<2;kk++){
        int sw = (kk*4+g) ^ (row&7);
        bfr[ni][kk] = *(const bf16x8*)(Lb + row*128 + sw*16);
      }
    }
    #pragma unroll
    for (int kk=0;kk<2;kk++)
      #pragma unroll
      for (int mi=0;mi<4;mi++)
        #pragma unroll
        for (int ni=0;ni<4;ni++)
          acc[mi][ni] = __builtin_amdgcn_mfma_f32_16x16x32_bf16(af[mi][kk], bfr[ni][kk], acc[mi][ni], 0,0,0);
    __syncthreads();
  }

  if (z == 2){
    #pragma unroll
    for (int ni=0;ni<4;ni++){
      int col = n0 + wc*64 + ni*16 + c;
      float bvv = bias[col];
      int hh = col>>6, d = col&63;
      #pragma unroll
      for (int mi=0;mi<4;mi++){
        int rowg = m0 + wr*64 + mi*16 + g*4;
        int bb = rowg>>11, s = rowg&2047;
        ushort4 pk = make_ushort4(f2b(acc[mi][ni][0] + bvv), f2b(acc[mi][ni][1] + bvv),
                                  f2b(acc[mi][ni][2] + bvv), f2b(acc[mi][ni][3] + bvv));
        *(ushort4*)(Vt + ((size_t)((bb*NH+hh)*HD + d))*BSEQ + s) = pk;
      }
    }
  } else {
    u16* O = (z==0)?Qo:(z==1)?Ko:(z==3)?COo:KCo;
    #pragma unroll
    for (int ni=0;ni<4;ni++){
      int col = n0 + wc*64 + ni*16 + c;
      float bvv = bias[col];
      #pragma unroll
      for (int mi=0;mi<4;mi++)
        #pragma unroll
        for (int r=0;r<4;r++){
          int rowg = m0 + wr*64 + mi*16 + g*4 + r;
          O[(size_t)rowg*AHS + col] = f2b((acc[mi][ni][r] + bvv) * oscale);
        }
    }
  }
}

// ---------------- span-kernel GEMM + softmax: CKP[8192][54] ----------------
__global__ __launch_bounds__(256) void k_ckgemm(const u16* __restrict__ QS, const u16* __restrict__ KCb,
    const u16* __restrict__ WckT, const float* __restrict__ bck, float* __restrict__ ckp)
{
  __shared__ char smem[73728];   // W 48K | CA 24K
  int tid = threadIdx.x, l = tid&63, w = tid>>6;
  int g = l>>4, c = l&15;
  int m0 = blockIdx.x * 32;
  char* Wl = smem;
  char* Al = smem + 49152;

  #pragma unroll
  for (int p=0; p<12; p++){
    int cid = p*256 + tid;
    int row = cid/48, chq = cid - row*48;
    int srow = row < 54 ? row : 53;
    int sch = (chq & ~7) | ((chq ^ row) & 7);
    gload_lds16(WckT + (size_t)srow*AHS + sch*8, Wl + p*4096 + w*1024);
  }
  #pragma unroll
  for (int p=0; p<6; p++){
    int cid = p*256 + tid;
    int row = cid/48, chq = cid - row*48;
    bf16x8 qv = *(const bf16x8*)(QS  + (size_t)(m0+row)*AHS + chq*8);
    bf16x8 kv = *(const bf16x8*)(KCb + (size_t)(m0+row)*AHS + chq*8);
    union { unsigned u[4]; bf16x8 v; } uu;
    #pragma unroll
    for (int j=0;j<4;j++){
      float lo = b2f((u16)qv[2*j])   * b2f((u16)kv[2*j])   * INVSCL;
      float hi = b2f((u16)qv[2*j+1]) * b2f((u16)kv[2*j+1]) * INVSCL;
      uu.u[j] = cvtpk_bf16(lo, hi);
    }
    int sch = (chq & ~7) | ((chq ^ row) & 7);
    *(bf16x8*)(Al + row*768 + sch*16) = uu.v;
  }
  __syncthreads();

  f32x4 zero = {0.f,0.f,0.f,0.f};
  f32x4 acc[2] = {zero, zero};
  #pragma unroll
  for (int ks=0; ks<12; ks++){
    bf16x8 af[2], bfr;
    #pragma unroll
    for (int mi=0;mi<2;mi++){
      int row = mi*16 + c;
      int chq = ks*4 + g;
      int sch = (chq & ~7) | ((chq ^ row) & 7);
      af[mi] = *(const bf16x8*)(Al + row*768 + sch*16);
    }
    {
      int row = w*16 + c;
      int chq = ks*4 + g;
      int sch = (chq & ~7) | ((chq ^ row) & 7);
      bfr = *(const bf16x8*)(Wl + row*768 + sch*16);
    }
    acc[0] = __builtin_amdgcn_mfma_f32_16x16x32_bf16(af[0], bfr, acc[0], 0,0,0);
    acc[1] = __builtin_amdgcn_mfma_f32_16x16x32_bf16(af[1], bfr, acc[1], 0,0,0);
  }

  float* LG = (float*)Al;
  __syncthreads();
  int n = w*16 + c;
  float bb = (n < 54) ? bck[n] : 0.f;
  #pragma unroll
  for (int mi=0;mi<2;mi++)
    #pragma unroll
    for (int r=0;r<4;r++){
      int m = mi*16 + g*4 + r;
      LG[m*64 + n] = acc[mi][r] + bb;
    }
  __syncthreads();
  if (tid < 192){
    int row = tid/6, hh = tid - (tid/6)*6;
    float lg9[9];
    float mx = -1e30f;
    #pragma unroll
    for (int j=0;j<9;j++){ lg9[j] = LG[row*64 + hh*9 + j]; mx = fmaxf(mx, lg9[j]); }
    float s = 0.f;
    #pragma unroll
    for (int j=0;j<9;j++){ lg9[j] = __expf(lg9[j]-mx); s += lg9[j]; }
    float inv = 1.f/s;
    #pragma unroll
    for (int j=0;j<9;j++) ckp[(size_t)(m0+row)*(NH*KK9) + hh*9 + j] = lg9[j]*inv;
  }
}

// ---------------- dynamic conv output (unfold x ck), writes out[:,:,384:768] ----------------
__global__ __launch_bounds__(384) void k_convout(const u16* __restrict__ CO, const float* __restrict__ ckp,
                                                 float* __restrict__ out)
{
  int tid = threadIdx.x;
  int pos = tid/96, lane96 = tid - pos*96;
  int sIdx = blockIdx.x*4 + pos;
  int b = sIdx>>11, s = sIdx&2047;
  int cc = lane96*4, h = cc>>6;
  __shared__ float ck[4][NH*KK9];
  if (lane96 < NH*KK9) ck[pos][lane96] = ckp[(size_t)sIdx*(NH*KK9) + lane96];
  __syncthreads();
  float a0=0.f,a1=0.f,a2=0.f,a3=0.f;
  #pragma unroll
  for (int k=0;k<KK9;k++){
    int ss = s + k - 4;
    if ((unsigned)ss < 2048u){
      ushort4 v = *(const ushort4*)(CO + ((size_t)((b<<11)+ss)*AHS + cc));
      float wk = ck[pos][h*KK9+k];
      a0 += b2f(v.x)*wk; a1 += b2f(v.y)*wk; a2 += b2f(v.z)*wk; a3 += b2f(v.w)*wk;
    }
  }
  float4 r = make_float4(a0,a1,a2,a3);
  *(float4*)(out + (size_t)sIdx*(2*AHS) + AHS + cc) = r;
}

// ---------------- flash attention (k-split x2, 32q/wave), f32 partials ----------------
// 768 blocks: (bh, qt, half). 4 waves x 32 q-rows = 128 q/block; 16 KV-iters of 64.
// Paired-iteration loop (compile-time LDS buffer parity). Swapped QK^T; in-register P;
// row-sums via MFMA-with-ones. f32 partial stores (64B segments, no write amplification).
#define AITER(T, P) do { \
    if ((T) < 15){ \
      int tn = (T)+1; \
      _Pragma("unroll") \
      for (int i=0;i<2;i++){ \
        int row = i*32 + rr; int sc = ch ^ (row&7); \
        gload_lds16(Kbase + (size_t)(tn*64 + row)*AHS + sc*8, Kls + ((P)^1)*8192 + i*4096 + w*1024); \
        gload_lds16(Vbase + (size_t)row*BSEQ + tn*64 + sc*8,  Vls + ((P)^1)*8192 + i*4096 + w*1024); \
      } \
    } \
    bf16x8 kf[4][2]; \
    _Pragma("unroll") \
    for (int ka=0;ka<4;ka++){ \
      int row = ka*16 + c; \
      _Pragma("unroll") \
      for (int kk=0;kk<2;kk++){ \
        int swz = (kk*4+g) ^ (row&7); \
        kf[ka][kk] = *(const bf16x8*)(Kls + (P)*8192 + row*128 + swz*16); \
      } \
    } \
    float4 mk[4]; \
    _Pragma("unroll") \
    for (int ka=0;ka<4;ka++) mk[ka] = *(const float4*)(mrow + (T)*64 + ka*16 + g*4); \
    unsigned pkw[2][4][2]; \
    _Pragma("unroll") \
    for (int qh=0;qh<2;qh++){ \
      f32x4 s4[4]; \
      _Pragma("unroll") \
      for (int ka=0;ka<4;ka++){ s4[ka][0]=mk[ka].x; s4[ka][1]=mk[ka].y; s4[ka][2]=mk[ka].z; s4[ka][3]=mk[ka].w; } \
      __builtin_amdgcn_s_setprio(1); \
      _Pragma("unroll") \
      for (int ka=0;ka<4;ka++){ \
        s4[ka] = __builtin_amdgcn_mfma_f32_16x16x32_bf16(kf[ka][0], aq[qh][0], s4[ka], 0,0,0); \
        s4[ka] = __builtin_amdgcn_mfma_f32_16x16x32_bf16(kf[ka][1], aq[qh][1], s4[ka], 0,0,0); \
      } \
      __builtin_amdgcn_s_setprio(0); \
      _Pragma("unroll") \
      for (int ka=0;ka<4;ka++){ \
        float p0 = exp2f(s4[ka][0]); \
        float p1 = exp2f(s4[ka][1]); \
        float p2 = exp2f(s4[ka][2]); \
        float p3 = exp2f(s4[ka][3]); \
        pkw[qh][ka][0] = cvtpk_bf16(p0, p1); \
        pkw[qh][ka][1] = cvtpk_bf16(p2, p3); \
      } \
    } \
    bf16x8 pa[2][2]; \
    _Pragma("unroll") \
    for (int qh=0;qh<2;qh++){ \
      _Pragma("unroll") \
      for (int kk=0;kk<2;kk++){ \
        unsigned e0 = pkw[qh][2*kk][0],   e1 = pkw[qh][2*kk][1]; \
        unsigned o0 = pkw[qh][2*kk+1][0], o1 = pkw[qh][2*kk+1][1]; \
        asm volatile("v_permlane32_swap_b32 %0, %1" : "+v"(e0), "+v"(o0)); \
        asm volatile("v_permlane16_swap_b32 %0, %1" : "+v"(e0), "+v"(o0)); \
        asm volatile("v_permlane32_swap_b32 %0, %1" : "+v"(e1), "+v"(o1)); \
        asm volatile("v_permlane16_swap_b32 %0, %1" : "+v"(e1), "+v"(o1)); \
        union { unsigned u[4]; bf16x8 v; } uu; \
        uu.u[0] = e0; uu.u[1] = e1; uu.u[2] = o0; uu.u[3] = o1; \
        pa[qh][kk] = uu.v; \
      } \
    } \
    bf16x8 vf[4][2]; \
    _Pragma("unroll") \
    for (int di=0;di<4;di++){ \
      int row = di*16 + c; \
      _Pragma("unroll") \
      for (int kk=0;kk<2;kk++){ \
        int swz = (kk*4+g) ^ (row&7); \
        vf[di][kk] = *(const bf16x8*)(Vls + (P)*8192 + row*128 + swz*16); \
      } \
    } \
    __builtin_amdgcn_s_setprio(1); \
    _Pragma("unroll") \
    for (int kk=0;kk<2;kk++){ \
      _Pragma("unroll") \
      for (int qh=0;qh<2;qh++){ \
        _Pragma("unroll") \
        for (int di=0;di<4;di++) \
          o[qh][di] = __builtin_amdgcn_mfma_f32_16x16x32_bf16(pa[qh][kk], vf[di][kk], o[qh][di], 0,0,0); \
        os[qh] = __builtin_amdgcn_mfma_f32_16x16x32_bf16(pa[qh][kk], ONES, os[qh], 0,0,0); \
      } \
    } \
    __builtin_amdgcn_s_setprio(0); \
    __syncthreads(); \
  } while(0)

__global__ __launch_bounds__(256,4) void k_attn(const u16* __restrict__ QS, const u16* __restrict__ Kb,
    const u16* __restrict__ Vt, const float* __restrict__ M8,
    float* __restrict__ OP, float* __restrict__ LS)
{
  __shared__ char smem[32768]; // K dbuf 16K | V dbuf 16K
  int tid = threadIdx.x, l = tid&63, w = tid>>6;
  int g = l>>4, c = l&15;
  // bijective XCD swizzle over 768 blocks: 96/XCD = 3 bh per XCD
  int n = blockIdx.x;
  int sw = (n & 7) * 96 + (n >> 3);
  int bh = sw >> 5, rem = sw & 31;
  int qt = rem >> 1, half = rem & 1;
  int b = bh/NH, h = bh - b*NH;

  char* Kls = smem;
  char* Vls = smem + 16384;

  int q0 = qt*128 + w*32;
  bf16x8 aq[2][2];
  #pragma unroll
  for (int qh=0;qh<2;qh++)
    #pragma unroll
    for (int kk=0;kk<2;kk++)
      aq[qh][kk] = *(const bf16x8*)(QS + (size_t)(b*BSEQ + q0 + qh*16 + c)*AHS + h*HD + kk*32 + g*8);

  const bf16x8 ONES = {(short)0x3F80,(short)0x3F80,(short)0x3F80,(short)0x3F80,
                       (short)0x3F80,(short)0x3F80,(short)0x3F80,(short)0x3F80};

  f32x4 o[2][4];
  #pragma unroll
  for (int i=0;i<2;i++)
    #pragma unroll
    for (int j=0;j<4;j++) o[i][j] = f32x4{0.f,0.f,0.f,0.f};
  f32x4 os[2] = {{0.f,0.f,0.f,0.f},{0.f,0.f,0.f,0.f}};

  int rr = w*8 + (l>>3), ch = l&7;
  const u16* Kbase = Kb + ((size_t)b*BSEQ + half*1024)*AHS + h*HD;
  const u16* Vbase = Vt + (size_t)bh*HD*BSEQ + half*1024;
  const float* mrow = M8 + b*BSEQ + half*1024;

  #pragma unroll
  for (int i=0;i<2;i++){
    int row = i*32 + rr; int sc = ch ^ (row&7);
    gload_lds16(Kbase + (size_t)row*AHS + sc*8, Kls + i*4096 + w*1024);
    gload_lds16(Vbase + (size_t)row*BSEQ + sc*8, Vls + i*4096 + w*1024);
  }
  __syncthreads();

  for (int tt=0; tt<8; tt++){
    AITER(2*tt, 0);
    AITER(2*tt+1, 1);
  }

  // f32 unnormalized partials; os[qh][r] = lsum for q=qh*16+g*4+r (replicated over c)
  #pragma unroll
  for (int qh=0;qh<2;qh++)
    #pragma unroll
    for (int r=0;r<4;r++){
      int rowq = q0 + qh*16 + g*4 + r;
      size_t rbase = (size_t)(half*MTOT + b*BSEQ + rowq);
      if (c == 0) LS[rbase*NH + h] = os[qh][r];
      #pragma unroll
      for (int di=0;di<4;di++)
        OP[rbase*AHS + h*HD + di*16 + c] = o[qh][di][r];
    }
}

// ---------------- combine k-split halves: out[:, :, 0:384] ----------------
__global__ __launch_bounds__(256) void k_attcomb(const float* __restrict__ OP, const float* __restrict__ LS,
    const float* __restrict__ hmask, float* __restrict__ out)
{
  int idx = blockIdx.x*256 + threadIdx.x;    // 0 .. 786431
  int row = idx/96;
  int cc = (idx - row*96)*4;
  int h = cc>>6;
  float4 v0 = *(const float4*)(OP + (size_t)row*AHS + cc);
  float4 v1 = *(const float4*)(OP + ((size_t)(MTOT + row))*AHS + cc);
  float lsum = LS[(size_t)row*NH + h] + LS[((size_t)(MTOT + row))*NH + h];
  float s = hmask[h] / lsum;
  float4 r = make_float4((v0.x+v1.x)*s, (v0.y+v1.y)*s, (v0.z+v1.z)*s, (v0.w+v1.w)*s);
  *(float4*)(out + (size_t)row*(2*AHS) + cc) = r;
}

extern "C" void kernel_launch(void* const* d_in, const int* in_sizes, int n_in,
                              void* d_out, int out_size, void* d_ws, size_t ws_size,
                              hipStream_t stream) {
  (void)in_sizes; (void)n_in; (void)out_size; (void)ws_size;
  const float* X     = (const float*)d_in[0];
  const float* amask = (const float*)d_in[1];
  const float* hmask = (const float*)d_in[2];
  const float* Wq  = (const float*)d_in[3];
  const float* bq  = (const float*)d_in[4];
  const float* Wk  = (const float*)d_in[5];
  const float* bk  = (const float*)d_in[6];
  const float* Wv  = (const float*)d_in[7];
  const float* bv  = (const float*)d_in[8];
  const float* dwk = (const float*)d_in[9];
  const float* pw  = (const float*)d_in[10];
  const float* cb  = (const float*)d_in[11];
  const float* Wck = (const float*)d_in[12];
  const float* bck = (const float*)d_in[13];
  const float* Wco = (const float*)d_in[14];
  const float* bco = (const float*)d_in[15];
  float* out = (float*)d_out;

  char* p = (char*)d_ws;
  u16* XBF  = (u16*)p; p += (size_t)MTOT*C_IN*2;
  u16* DWBF = (u16*)p; p += (size_t)MTOT*C_IN*2;
  u16* WTQ  = (u16*)p; p += (size_t)C_IN*AHS*2;
  u16* WTK  = (u16*)p; p += (size_t)C_IN*AHS*2;
  u16* WTV  = (u16*)p; p += (size_t)C_IN*AHS*2;
  u16* WTCO = (u16*)p; p += (size_t)C_IN*AHS*2;
  u16* WTPW = (u16*)p; p += (size_t)C_IN*AHS*2;
  u16* WCKT = (u16*)p; p += (size_t)(NH*KK9)*AHS*2;
  u16* QS   = (u16*)p; p += (size_t)MTOT*AHS*2;
  u16* KB   = (u16*)p; p += (size_t)MTOT*AHS*2;
  u16* COB  = (u16*)p; p += (size_t)MTOT*AHS*2;
  u16* KCB  = (u16*)p; p += (size_t)MTOT*AHS*2;
  u16* VT   = (u16*)p; p += (size_t)MTOT*AHS*2;
  float* CKP = (float*)p; p += (size_t)MTOT*(NH*KK9)*4;
  float* M8  = (float*)p; p += (size_t)MTOT*4;

  // attn partials alias buffers dead after k_gemm5:
  float* OP = (float*)XBF;   // 2 * 8192*384*4B == XBF+DWBF region (25.2MB)
  float* LS = (float*)WTQ;   // 2 * 8192*6*4B = 393KB < WTQ

  dim3 tb(32,8);
  k_transpose_cast5<<<dim3(24,12,5),tb,0,stream>>>(Wq, Wk, Wv, Wco, pw, WTQ, WTK, WTV, WTCO, WTPW);
  k_transpose_cast<<<dim3(12,2), tb,0,stream>>>(Wck, WCKT, AHS, NH*KK9);

  k_prep_x<<<MTOT,192,0,stream>>>(X, dwk, amask, XBF, DWBF, M8);

  k_gemm5<<<dim3(64,3,5),256,0,stream>>>(XBF, DWBF, WTQ, WTK, WTV, WTCO, WTPW,
                                         bq, bk, bv, bco, cb,
                                         QS, KB, VT, COB, KCB);

  k_ckgemm<<<256,256,0,stream>>>(QS, KCB, WCKT, bck, CKP);
  k_convout<<<2048,384,0,stream>>>(COB, CKP, out);
  k_attn<<<768,256,0,stream>>>(QS, KB, VT, M8, OP, LS);
  k_attcomb<<<3072,256,0,stream>>>(OP, LS, hmask, out);
}

// Round 10
// 165.401 us; speedup vs baseline: 1.4945x; 1.4945x over previous
//
#include <hip/hip_runtime.h>
#include <hip/hip_bf16.h>
#include <stdint.h>

typedef unsigned short u16;
typedef short bf16x8 __attribute__((ext_vector_type(8)));
typedef float f32x4 __attribute__((ext_vector_type(4)));

#define C_IN 768
#define AHS 384
#define NH 6
#define HD 64
#define KK9 9
#define BSEQ 2048
#define MTOT 8192

__device__ __forceinline__ float b2f(u16 u){
  union { unsigned u; float f; } v; v.u = ((unsigned)u) << 16; return v.f;
}
__device__ __forceinline__ u16 f2b(float f){
  union { float f; unsigned u; } v; v.f = f;
  unsigned r = (v.u + 0x7FFFu + ((v.u >> 16) & 1u)) >> 16;
  return (u16)r;
}
__device__ __forceinline__ void gload_lds16(const void* g, void* l){
  __builtin_amdgcn_global_load_lds((const __attribute__((address_space(1))) unsigned int*)g,
                                   (__attribute__((address_space(3))) unsigned int*)l, 16, 0, 0);
}
__device__ __forceinline__ unsigned cvtpk_bf16(float lo, float hi){
  unsigned w;
  asm("v_cvt_pk_bf16_f32 %0, %1, %2" : "=v"(w) : "v"(lo), "v"(hi));
  return w;
}

#define SCL 0.18033688011112042f   // 0.125 * log2(e)
#define INVSCL 5.545177444479562f  // 8 * ln(2)
#define LOG2E 1.4426950408889634f

// ---------------- transpose + cast f32[R][C] -> bf16[C][R], 5 weights fused ----------------
__global__ void k_transpose_cast5(const float* __restrict__ s0, const float* __restrict__ s1,
                                  const float* __restrict__ s2, const float* __restrict__ s3,
                                  const float* __restrict__ s4,
                                  u16* __restrict__ d0, u16* __restrict__ d1, u16* __restrict__ d2,
                                  u16* __restrict__ d3, u16* __restrict__ d4){
  __shared__ float t[32][33];
  int z = blockIdx.z;
  const float* src = (z==0)?s0:(z==1)?s1:(z==2)?s2:(z==3)?s3:s4;
  u16* dst = (z==0)?d0:(z==1)?d1:(z==2)?d2:(z==3)?d3:d4;
  const int R = C_IN, C = AHS;
  int r0 = blockIdx.x*32, c0 = blockIdx.y*32;
  int tx = threadIdx.x, ty = threadIdx.y;
  #pragma unroll
  for (int j=0;j<4;j++){
    int r = r0 + ty + j*8, c = c0 + tx;
    t[ty+j*8][tx] = src[(size_t)r*C + c];
  }
  __syncthreads();
  #pragma unroll
  for (int j=0;j<4;j++){
    int c = c0 + ty + j*8, r = r0 + tx;
    dst[(size_t)c*R + r] = f2b(t[tx][ty+j*8]);
  }
}

__global__ void k_transpose_cast(const float* __restrict__ src, u16* __restrict__ dst, int R, int C){
  __shared__ float t[32][33];
  int r0 = blockIdx.x*32, c0 = blockIdx.y*32;
  int tx = threadIdx.x, ty = threadIdx.y;
  #pragma unroll
  for (int j=0;j<4;j++){
    int r = r0 + ty + j*8, c = c0 + tx;
    t[ty+j*8][tx] = (r<R && c<C) ? src[(size_t)r*C + c] : 0.f;
  }
  __syncthreads();
  #pragma unroll
  for (int j=0;j<4;j++){
    int c = c0 + ty + j*8, r = r0 + tx;
    if (r<R && c<C) dst[(size_t)c*R + r] = f2b(t[tx][ty+j*8]);
  }
}

// ---------------- X cast + depthwise conv (SAME), plus M8 = amask*log2e ----------------
__global__ __launch_bounds__(192) void k_prep_x(const float* __restrict__ X, const float* __restrict__ dwk,
                          const float* __restrict__ amask,
                          u16* __restrict__ Xbf, u16* __restrict__ DWbf, float* __restrict__ M8){
  int blk = blockIdx.x; int b = blk>>11; int s = blk&2047;
  int c0 = threadIdx.x*4;
  if (threadIdx.x == 0) M8[blk] = amask[blk] * LOG2E;
  size_t base = (size_t)blk*C_IN + c0;
  float4 xc = *(const float4*)(X + base);
  *(ushort4*)(Xbf + base) = make_ushort4(f2b(xc.x), f2b(xc.y), f2b(xc.z), f2b(xc.w));
  float a0=0.f,a1=0.f,a2=0.f,a3=0.f;
  #pragma unroll
  for (int k=0;k<KK9;k++){
    int ss = s + k - 4;
    if ((unsigned)ss < 2048u){
      float4 xv = *(const float4*)(X + ((size_t)((b<<11)+ss)*C_IN + c0));
      float4 wv = *(const float4*)(dwk + k*C_IN + c0);
      a0 += xv.x*wv.x; a1 += xv.y*wv.y; a2 += xv.z*wv.z; a3 += xv.w*wv.w;
    }
  }
  *(ushort4*)(DWbf + base) = make_ushort4(f2b(a0), f2b(a1), f2b(a2), f2b(a3));
}

// ---------------- 5-way fused projection GEMM: [8192,768]x[768,384] ----------------
// z: 0=Q(-> scaled by SCL) 1=K 2=V(-> transposed Vt) 3=CO 4=KeyConv
__global__ __launch_bounds__(256) void k_gemm5(
    const u16* __restrict__ Xbf, const u16* __restrict__ DWbf,
    const u16* __restrict__ WtQ, const u16* __restrict__ WtK, const u16* __restrict__ WtV,
    const u16* __restrict__ WtCO, const u16* __restrict__ WtPW,
    const float* __restrict__ bq, const float* __restrict__ bk_, const float* __restrict__ bv,
    const float* __restrict__ bco, const float* __restrict__ bcv,
    u16* __restrict__ Qo, u16* __restrict__ Ko, u16* __restrict__ Vt,
    u16* __restrict__ COo, u16* __restrict__ KCo)
{
  __shared__ char smem[32768];
  int tid = threadIdx.x, l = tid&63, w = tid>>6;
  int g = l>>4, c = l&15;
  int wr = w>>1, wc = w&1;
  int mt = blockIdx.x, nt = blockIdx.y, z = blockIdx.z;
  const u16* A = (z==4) ? DWbf : Xbf;
  const u16* B = (z==0)?WtQ:(z==1)?WtK:(z==2)?WtV:(z==3)?WtCO:WtPW;
  const float* bias = (z==0)?bq:(z==1)?bk_:(z==2)?bv:(z==3)?bco:bcv;
  float oscale = (z==0) ? SCL : 1.0f;

  char* La = smem; char* Lb = smem + 16384;
  int m0 = mt*128, n0 = nt*128;

  f32x4 zero = {0.f,0.f,0.f,0.f};
  f32x4 acc[4][4];
  #pragma unroll
  for (int i=0;i<4;i++)
    #pragma unroll
    for (int j=0;j<4;j++) acc[i][j] = zero;

  int rr = w*8 + (l>>3);
  int ch = l&7;

  for (int kt=0; kt<12; kt++){
    #pragma unroll
    for (int i=0;i<4;i++){
      int row = i*32 + rr;
      int sc = ch ^ (row&7);
      gload_lds16(A + (size_t)(m0+row)*C_IN + kt*64 + sc*8, La + i*4096 + w*1024);
      gload_lds16(B + (size_t)(n0+row)*C_IN + kt*64 + sc*8, Lb + i*4096 + w*1024);
    }
    __syncthreads();
    bf16x8 af[4][2], bfr[4][2];
    #pragma unroll
    for (int mi=0;mi<4;mi++){
      int row = wr*64 + mi*16 + c;
      #pragma unroll
      for (int kk=0;kk<2;kk++){
        int sw = (kk*4+g) ^ (row&7);
        af[mi][kk] = *(const bf16x8*)(La + row*128 + sw*16);
      }
    }
    #pragma unroll
    for (int ni=0;ni<4;ni++){
      int row = wc*64 + ni*16 + c;
      #pragma unroll
      for (int kk=0;kk<2;kk++){
        int sw = (kk*4+g) ^ (row&7);
        bfr[ni][kk] = *(const bf16x8*)(Lb + row*128 + sw*16);
      }
    }
    #pragma unroll
    for (int kk=0;kk<2;kk++)
      #pragma unroll
      for (int mi=0;mi<4;mi++)
        #pragma unroll
        for (int ni=0;ni<4;ni++)
          acc[mi][ni] = __builtin_amdgcn_mfma_f32_16x16x32_bf16(af[mi][kk], bfr[ni][kk], acc[mi][ni], 0,0,0);
    __syncthreads();
  }

  if (z == 2){
    #pragma unroll
    for (int ni=0;ni<4;ni++){
      int col = n0 + wc*64 + ni*16 + c;
      float bvv = bias[col];
      int hh = col>>6, d = col&63;
      #pragma unroll
      for (int mi=0;mi<4;mi++){
        int rowg = m0 + wr*64 + mi*16 + g*4;
        int bb = rowg>>11, s = rowg&2047;
        ushort4 pk = make_ushort4(f2b(acc[mi][ni][0] + bvv), f2b(acc[mi][ni][1] + bvv),
                                  f2b(acc[mi][ni][2] + bvv), f2b(acc[mi][ni][3] + bvv));
        *(ushort4*)(Vt + ((size_t)((bb*NH+hh)*HD + d))*BSEQ + s) = pk;
      }
    }
  } else {
    u16* O = (z==0)?Qo:(z==1)?Ko:(z==3)?COo:KCo;
    #pragma unroll
    for (int ni=0;ni<4;ni++){
      int col = n0 + wc*64 + ni*16 + c;
      float bvv = bias[col];
      #pragma unroll
      for (int mi=0;mi<4;mi++)
        #pragma unroll
        for (int r=0;r<4;r++){
          int rowg = m0 + wr*64 + mi*16 + g*4 + r;
          O[(size_t)rowg*AHS + col] = f2b((acc[mi][ni][r] + bvv) * oscale);
        }
    }
  }
}

// ---------------- span-kernel GEMM + softmax: CKP[8192][54] ----------------
__global__ __launch_bounds__(256) void k_ckgemm(const u16* __restrict__ QS, const u16* __restrict__ KCb,
    const u16* __restrict__ WckT, const float* __restrict__ bck, float* __restrict__ ckp)
{
  __shared__ char smem[73728];   // W 48K | CA 24K
  int tid = threadIdx.x, l = tid&63, w = tid>>6;
  int g = l>>4, c = l&15;
  int m0 = blockIdx.x * 32;
  char* Wl = smem;
  char* Al = smem + 49152;

  #pragma unroll
  for (int p=0; p<12; p++){
    int cid = p*256 + tid;
    int row = cid/48, chq = cid - row*48;
    int srow = row < 54 ? row : 53;
    int sch = (chq & ~7) | ((chq ^ row) & 7);
    gload_lds16(WckT + (size_t)srow*AHS + sch*8, Wl + p*4096 + w*1024);
  }
  #pragma unroll
  for (int p=0; p<6; p++){
    int cid = p*256 + tid;
    int row = cid/48, chq = cid - row*48;
    bf16x8 qv = *(const bf16x8*)(QS  + (size_t)(m0+row)*AHS + chq*8);
    bf16x8 kv = *(const bf16x8*)(KCb + (size_t)(m0+row)*AHS + chq*8);
    union { unsigned u[4]; bf16x8 v; } uu;
    #pragma unroll
    for (int j=0;j<4;j++){
      float lo = b2f((u16)qv[2*j])   * b2f((u16)kv[2*j])   * INVSCL;
      float hi = b2f((u16)qv[2*j+1]) * b2f((u16)kv[2*j+1]) * INVSCL;
      uu.u[j] = cvtpk_bf16(lo, hi);
    }
    int sch = (chq & ~7) | ((chq ^ row) & 7);
    *(bf16x8*)(Al + row*768 + sch*16) = uu.v;
  }
  __syncthreads();

  f32x4 zero = {0.f,0.f,0.f,0.f};
  f32x4 acc[2] = {zero, zero};
  #pragma unroll
  for (int ks=0; ks<12; ks++){
    bf16x8 af[2], bfr;
    #pragma unroll
    for (int mi=0;mi<2;mi++){
      int row = mi*16 + c;
      int chq = ks*4 + g;
      int sch = (chq & ~7) | ((chq ^ row) & 7);
      af[mi] = *(const bf16x8*)(Al + row*768 + sch*16);
    }
    {
      int row = w*16 + c;
      int chq = ks*4 + g;
      int sch = (chq & ~7) | ((chq ^ row) & 7);
      bfr = *(const bf16x8*)(Wl + row*768 + sch*16);
    }
    acc[0] = __builtin_amdgcn_mfma_f32_16x16x32_bf16(af[0], bfr, acc[0], 0,0,0);
    acc[1] = __builtin_amdgcn_mfma_f32_16x16x32_bf16(af[1], bfr, acc[1], 0,0,0);
  }

  float* LG = (float*)Al;
  __syncthreads();
  int n = w*16 + c;
  float bb = (n < 54) ? bck[n] : 0.f;
  #pragma unroll
  for (int mi=0;mi<2;mi++)
    #pragma unroll
    for (int r=0;r<4;r++){
      int m = mi*16 + g*4 + r;
      LG[m*64 + n] = acc[mi][r] + bb;
    }
  __syncthreads();
  if (tid < 192){
    int row = tid/6, hh = tid - (tid/6)*6;
    float lg9[9];
    float mx = -1e30f;
    #pragma unroll
    for (int j=0;j<9;j++){ lg9[j] = LG[row*64 + hh*9 + j]; mx = fmaxf(mx, lg9[j]); }
    float s = 0.f;
    #pragma unroll
    for (int j=0;j<9;j++){ lg9[j] = __expf(lg9[j]-mx); s += lg9[j]; }
    float inv = 1.f/s;
    #pragma unroll
    for (int j=0;j<9;j++) ckp[(size_t)(m0+row)*(NH*KK9) + hh*9 + j] = lg9[j]*inv;
  }
}

// ---------------- dynamic conv output (unfold x ck), writes out[:,:,384:768] ----------------
__global__ __launch_bounds__(384) void k_convout(const u16* __restrict__ CO, const float* __restrict__ ckp,
                                                 float* __restrict__ out)
{
  int tid = threadIdx.x;
  int pos = tid/96, lane96 = tid - pos*96;
  int sIdx = blockIdx.x*4 + pos;
  int b = sIdx>>11, s = sIdx&2047;
  int cc = lane96*4, h = cc>>6;
  __shared__ float ck[4][NH*KK9];
  if (lane96 < NH*KK9) ck[pos][lane96] = ckp[(size_t)sIdx*(NH*KK9) + lane96];
  __syncthreads();
  float a0=0.f,a1=0.f,a2=0.f,a3=0.f;
  #pragma unroll
  for (int k=0;k<KK9;k++){
    int ss = s + k - 4;
    if ((unsigned)ss < 2048u){
      ushort4 v = *(const ushort4*)(CO + ((size_t)((b<<11)+ss)*AHS + cc));
      float wk = ck[pos][h*KK9+k];
      a0 += b2f(v.x)*wk; a1 += b2f(v.y)*wk; a2 += b2f(v.z)*wk; a3 += b2f(v.w)*wk;
    }
  }
  float4 r = make_float4(a0,a1,a2,a3);
  *(float4*)(out + (size_t)sIdx*(2*AHS) + AHS + cc) = r;
}

// ---------------- flash attention (k-split x2, 32q/wave), f32 partials ----------------
// 768 blocks: (bh, qt, half). 4 waves x 32 q-rows = 128 q/block; 16 KV-iters of 64.
// NOTE: plain __launch_bounds__(256) — the ",4" variant capped VGPRs at 64 and spilled
// ~120 live regs to scratch (R7/R8: 10-13x WRITE_SIZE inflation).
#define AITER(T, P) do { \
    if ((T) < 15){ \
      int tn = (T)+1; \
      _Pragma("unroll") \
      for (int i=0;i<2;i++){ \
        int row = i*32 + rr; int sc = ch ^ (row&7); \
        gload_lds16(Kbase + (size_t)(tn*64 + row)*AHS + sc*8, Kls + ((P)^1)*8192 + i*4096 + w*1024); \
        gload_lds16(Vbase + (size_t)row*BSEQ + tn*64 + sc*8,  Vls + ((P)^1)*8192 + i*4096 + w*1024); \
      } \
    } \
    bf16x8 kf[4][2]; \
    _Pragma("unroll") \
    for (int ka=0;ka<4;ka++){ \
      int row = ka*16 + c; \
      _Pragma("unroll") \
      for (int kk=0;kk<2;kk++){ \
        int swz = (kk*4+g) ^ (row&7); \
        kf[ka][kk] = *(const bf16x8*)(Kls + (P)*8192 + row*128 + swz*16); \
      } \
    } \
    float4 mk[4]; \
    _Pragma("unroll") \
    for (int ka=0;ka<4;ka++) mk[ka] = *(const float4*)(mrow + (T)*64 + ka*16 + g*4); \
    unsigned pkw[2][4][2]; \
    _Pragma("unroll") \
    for (int qh=0;qh<2;qh++){ \
      f32x4 s4[4]; \
      _Pragma("unroll") \
      for (int ka=0;ka<4;ka++){ s4[ka][0]=mk[ka].x; s4[ka][1]=mk[ka].y; s4[ka][2]=mk[ka].z; s4[ka][3]=mk[ka].w; } \
      __builtin_amdgcn_s_setprio(1); \
      _Pragma("unroll") \
      for (int ka=0;ka<4;ka++){ \
        s4[ka] = __builtin_amdgcn_mfma_f32_16x16x32_bf16(kf[ka][0], aq[qh][0], s4[ka], 0,0,0); \
        s4[ka] = __builtin_amdgcn_mfma_f32_16x16x32_bf16(kf[ka][1], aq[qh][1], s4[ka], 0,0,0); \
      } \
      __builtin_amdgcn_s_setprio(0); \
      _Pragma("unroll") \
      for (int ka=0;ka<4;ka++){ \
        float p0 = exp2f(s4[ka][0]); \
        float p1 = exp2f(s4[ka][1]); \
        float p2 = exp2f(s4[ka][2]); \
        float p3 = exp2f(s4[ka][3]); \
        pkw[qh][ka][0] = cvtpk_bf16(p0, p1); \
        pkw[qh][ka][1] = cvtpk_bf16(p2, p3); \
      } \
    } \
    bf16x8 pa[2][2]; \
    _Pragma("unroll") \
    for (int qh=0;qh<2;qh++){ \
      _Pragma("unroll") \
      for (int kk=0;kk<2;kk++){ \
        unsigned e0 = pkw[qh][2*kk][0],   e1 = pkw[qh][2*kk][1]; \
        unsigned o0 = pkw[qh][2*kk+1][0], o1 = pkw[qh][2*kk+1][1]; \
        asm volatile("v_permlane32_swap_b32 %0, %1" : "+v"(e0), "+v"(o0)); \
        asm volatile("v_permlane16_swap_b32 %0, %1" : "+v"(e0), "+v"(o0)); \
        asm volatile("v_permlane32_swap_b32 %0, %1" : "+v"(e1), "+v"(o1)); \
        asm volatile("v_permlane16_swap_b32 %0, %1" : "+v"(e1), "+v"(o1)); \
        union { unsigned u[4]; bf16x8 v; } uu; \
        uu.u[0] = e0; uu.u[1] = e1; uu.u[2] = o0; uu.u[3] = o1; \
        pa[qh][kk] = uu.v; \
      } \
    } \
    bf16x8 vf[4][2]; \
    _Pragma("unroll") \
    for (int di=0;di<4;di++){ \
      int row = di*16 + c; \
      _Pragma("unroll") \
      for (int kk=0;kk<2;kk++){ \
        int swz = (kk*4+g) ^ (row&7); \
        vf[di][kk] = *(const bf16x8*)(Vls + (P)*8192 + row*128 + swz*16); \
      } \
    } \
    __builtin_amdgcn_s_setprio(1); \
    _Pragma("unroll") \
    for (int kk=0;kk<2;kk++){ \
      _Pragma("unroll") \
      for (int qh=0;qh<2;qh++){ \
        _Pragma("unroll") \
        for (int di=0;di<4;di++) \
          o[qh][di] = __builtin_amdgcn_mfma_f32_16x16x32_bf16(pa[qh][kk], vf[di][kk], o[qh][di], 0,0,0); \
        os[qh] = __builtin_amdgcn_mfma_f32_16x16x32_bf16(pa[qh][kk], ONES, os[qh], 0,0,0); \
      } \
    } \
    __builtin_amdgcn_s_setprio(0); \
    __syncthreads(); \
  } while(0)

__global__ __launch_bounds__(256) void k_attn(const u16* __restrict__ QS, const u16* __restrict__ Kb,
    const u16* __restrict__ Vt, const float* __restrict__ M8,
    float* __restrict__ OP, float* __restrict__ LS)
{
  __shared__ char smem[32768]; // K dbuf 16K | V dbuf 16K
  int tid = threadIdx.x, l = tid&63, w = tid>>6;
  int g = l>>4, c = l&15;
  // bijective XCD swizzle over 768 blocks: 96/XCD = 3 bh per XCD
  int n = blockIdx.x;
  int sw = (n & 7) * 96 + (n >> 3);
  int bh = sw >> 5, rem = sw & 31;
  int qt = rem >> 1, half = rem & 1;
  int b = bh/NH, h = bh - b*NH;

  char* Kls = smem;
  char* Vls = smem + 16384;

  int q0 = qt*128 + w*32;
  bf16x8 aq[2][2];
  #pragma unroll
  for (int qh=0;qh<2;qh++)
    #pragma unroll
    for (int kk=0;kk<2;kk++)
      aq[qh][kk] = *(const bf16x8*)(QS + (size_t)(b*BSEQ + q0 + qh*16 + c)*AHS + h*HD + kk*32 + g*8);

  const bf16x8 ONES = {(short)0x3F80,(short)0x3F80,(short)0x3F80,(short)0x3F80,
                       (short)0x3F80,(short)0x3F80,(short)0x3F80,(short)0x3F80};

  f32x4 o[2][4];
  #pragma unroll
  for (int i=0;i<2;i++)
    #pragma unroll
    for (int j=0;j<4;j++) o[i][j] = f32x4{0.f,0.f,0.f,0.f};
  f32x4 os[2] = {{0.f,0.f,0.f,0.f},{0.f,0.f,0.f,0.f}};

  int rr = w*8 + (l>>3), ch = l&7;
  const u16* Kbase = Kb + ((size_t)b*BSEQ + half*1024)*AHS + h*HD;
  const u16* Vbase = Vt + (size_t)bh*HD*BSEQ + half*1024;
  const float* mrow = M8 + b*BSEQ + half*1024;

  #pragma unroll
  for (int i=0;i<2;i++){
    int row = i*32 + rr; int sc = ch ^ (row&7);
    gload_lds16(Kbase + (size_t)row*AHS + sc*8, Kls + i*4096 + w*1024);
    gload_lds16(Vbase + (size_t)row*BSEQ + sc*8, Vls + i*4096 + w*1024);
  }
  __syncthreads();

  for (int tt=0; tt<8; tt++){
    AITER(2*tt, 0);
    AITER(2*tt+1, 1);
  }

  // f32 unnormalized partials; os[qh][r] = lsum for q=qh*16+g*4+r (replicated over c)
  #pragma unroll
  for (int qh=0;qh<2;qh++)
    #pragma unroll
    for (int r=0;r<4;r++){
      int rowq = q0 + qh*16 + g*4 + r;
      size_t rbase = (size_t)(half*MTOT + b*BSEQ + rowq);
      if (c == 0) LS[rbase*NH + h] = os[qh][r];
      #pragma unroll
      for (int di=0;di<4;di++)
        OP[rbase*AHS + h*HD + di*16 + c] = o[qh][di][r];
    }
}

// ---------------- combine k-split halves: out[:, :, 0:384] ----------------
__global__ __launch_bounds__(256) void k_attcomb(const float* __restrict__ OP, const float* __restrict__ LS,
    const float* __restrict__ hmask, float* __restrict__ out)
{
  int idx = blockIdx.x*256 + threadIdx.x;    // 0 .. 786431
  int row = idx/96;
  int cc = (idx - row*96)*4;
  int h = cc>>6;
  float4 v0 = *(const float4*)(OP + (size_t)row*AHS + cc);
  float4 v1 = *(const float4*)(OP + ((size_t)(MTOT + row))*AHS + cc);
  float lsum = LS[(size_t)row*NH + h] + LS[((size_t)(MTOT + row))*NH + h];
  float s = hmask[h] / lsum;
  float4 r = make_float4((v0.x+v1.x)*s, (v0.y+v1.y)*s, (v0.z+v1.z)*s, (v0.w+v1.w)*s);
  *(float4*)(out + (size_t)row*(2*AHS) + cc) = r;
}

extern "C" void kernel_launch(void* const* d_in, const int* in_sizes, int n_in,
                              void* d_out, int out_size, void* d_ws, size_t ws_size,
                              hipStream_t stream) {
  (void)in_sizes; (void)n_in; (void)out_size; (void)ws_size;
  const float* X     = (const float*)d_in[0];
  const float* amask = (const float*)d_in[1];
  const float* hmask = (const float*)d_in[2];
  const float* Wq  = (const float*)d_in[3];
  const float* bq  = (const float*)d_in[4];
  const float* Wk  = (const float*)d_in[5];
  const float* bk  = (const float*)d_in[6];
  const float* Wv  = (const float*)d_in[7];
  const float* bv  = (const float*)d_in[8];
  const float* dwk = (const float*)d_in[9];
  const float* pw  = (const float*)d_in[10];
  const float* cb  = (const float*)d_in[11];
  const float* Wck = (const float*)d_in[12];
  const float* bck = (const float*)d_in[13];
  const float* Wco = (const float*)d_in[14];
  const float* bco = (const float*)d_in[15];
  float* out = (float*)d_out;

  char* p = (char*)d_ws;
  u16* XBF  = (u16*)p; p += (size_t)MTOT*C_IN*2;
  u16* DWBF = (u16*)p; p += (size_t)MTOT*C_IN*2;
  u16* WTQ  = (u16*)p; p += (size_t)C_IN*AHS*2;
  u16* WTK  = (u16*)p; p += (size_t)C_IN*AHS*2;
  u16* WTV  = (u16*)p; p += (size_t)C_IN*AHS*2;
  u16* WTCO = (u16*)p; p += (size_t)C_IN*AHS*2;
  u16* WTPW = (u16*)p; p += (size_t)C_IN*AHS*2;
  u16* WCKT = (u16*)p; p += (size_t)(NH*KK9)*AHS*2;
  u16* QS   = (u16*)p; p += (size_t)MTOT*AHS*2;
  u16* KB   = (u16*)p; p += (size_t)MTOT*AHS*2;
  u16* COB  = (u16*)p; p += (size_t)MTOT*AHS*2;
  u16* KCB  = (u16*)p; p += (size_t)MTOT*AHS*2;
  u16* VT   = (u16*)p; p += (size_t)MTOT*AHS*2;
  float* CKP = (float*)p; p += (size_t)MTOT*(NH*KK9)*4;
  float* M8  = (float*)p; p += (size_t)MTOT*4;

  // attn partials alias buffers dead after k_gemm5:
  float* OP = (float*)XBF;   // 2 * 8192*384*4B == XBF+DWBF region (25.2MB)
  float* LS = (float*)WTQ;   // 2 * 8192*6*4B = 393KB < WTQ

  dim3 tb(32,8);
  k_transpose_cast5<<<dim3(24,12,5),tb,0,stream>>>(Wq, Wk, Wv, Wco, pw, WTQ, WTK, WTV, WTCO, WTPW);
  k_transpose_cast<<<dim3(12,2), tb,0,stream>>>(Wck, WCKT, AHS, NH*KK9);

  k_prep_x<<<MTOT,192,0,stream>>>(X, dwk, amask, XBF, DWBF, M8);

  k_gemm5<<<dim3(64,3,5),256,0,stream>>>(XBF, DWBF, WTQ, WTK, WTV, WTCO, WTPW,
                                         bq, bk, bv, bco, cb,
                                         QS, KB, VT, COB, KCB);

  k_ckgemm<<<256,256,0,stream>>>(QS, KCB, WCKT, bck, CKP);
  k_convout<<<2048,384,0,stream>>>(COB, CKP, out);
  k_attn<<<768,256,0,stream>>>(QS, KB, VT, M8, OP, LS);
  k_attcomb<<<3072,256,0,stream>>>(OP, LS, hmask, out);
}

// Round 11
// 158.785 us; speedup vs baseline: 1.5567x; 1.0417x over previous
//
#include <hip/hip_runtime.h>
#include <hip/hip_bf16.h>
#include <stdint.h>

typedef unsigned short u16;
typedef short bf16x8 __attribute__((ext_vector_type(8)));
typedef float f32x4 __attribute__((ext_vector_type(4)));

#define C_IN 768
#define AHS 384
#define NH 6
#define HD 64
#define KK9 9
#define BSEQ 2048
#define MTOT 8192

__device__ __forceinline__ float b2f(u16 u){
  union { unsigned u; float f; } v; v.u = ((unsigned)u) << 16; return v.f;
}
__device__ __forceinline__ u16 f2b(float f){
  union { float f; unsigned u; } v; v.f = f;
  unsigned r = (v.u + 0x7FFFu + ((v.u >> 16) & 1u)) >> 16;
  return (u16)r;
}
__device__ __forceinline__ void gload_lds16(const void* g, void* l){
  __builtin_amdgcn_global_load_lds((const __attribute__((address_space(1))) unsigned int*)g,
                                   (__attribute__((address_space(3))) unsigned int*)l, 16, 0, 0);
}
__device__ __forceinline__ unsigned cvtpk_bf16(float lo, float hi){
  unsigned w;
  asm("v_cvt_pk_bf16_f32 %0, %1, %2" : "=v"(w) : "v"(lo), "v"(hi));
  return w;
}

#define SCL 0.18033688011112042f   // 0.125 * log2(e)
#define INVSCL 5.545177444479562f  // 8 * ln(2)
#define LOG2E 1.4426950408889634f

// ---------------- transpose + cast f32[R][C] -> bf16[C][R], 5 weights fused ----------------
__global__ void k_transpose_cast5(const float* __restrict__ s0, const float* __restrict__ s1,
                                  const float* __restrict__ s2, const float* __restrict__ s3,
                                  const float* __restrict__ s4,
                                  u16* __restrict__ d0, u16* __restrict__ d1, u16* __restrict__ d2,
                                  u16* __restrict__ d3, u16* __restrict__ d4){
  __shared__ float t[32][33];
  int z = blockIdx.z;
  const float* src = (z==0)?s0:(z==1)?s1:(z==2)?s2:(z==3)?s3:s4;
  u16* dst = (z==0)?d0:(z==1)?d1:(z==2)?d2:(z==3)?d3:d4;
  const int R = C_IN, C = AHS;
  int r0 = blockIdx.x*32, c0 = blockIdx.y*32;
  int tx = threadIdx.x, ty = threadIdx.y;
  #pragma unroll
  for (int j=0;j<4;j++){
    int r = r0 + ty + j*8, c = c0 + tx;
    t[ty+j*8][tx] = src[(size_t)r*C + c];
  }
  __syncthreads();
  #pragma unroll
  for (int j=0;j<4;j++){
    int c = c0 + ty + j*8, r = r0 + tx;
    dst[(size_t)c*R + r] = f2b(t[tx][ty+j*8]);
  }
}

__global__ void k_transpose_cast(const float* __restrict__ src, u16* __restrict__ dst, int R, int C){
  __shared__ float t[32][33];
  int r0 = blockIdx.x*32, c0 = blockIdx.y*32;
  int tx = threadIdx.x, ty = threadIdx.y;
  #pragma unroll
  for (int j=0;j<4;j++){
    int r = r0 + ty + j*8, c = c0 + tx;
    t[ty+j*8][tx] = (r<R && c<C) ? src[(size_t)r*C + c] : 0.f;
  }
  __syncthreads();
  #pragma unroll
  for (int j=0;j<4;j++){
    int c = c0 + ty + j*8, r = r0 + tx;
    if (r<R && c<C) dst[(size_t)c*R + r] = f2b(t[tx][ty+j*8]);
  }
}

// ---------------- X cast + depthwise conv (SAME), plus M8 = amask*log2e ----------------
__global__ __launch_bounds__(192) void k_prep_x(const float* __restrict__ X, const float* __restrict__ dwk,
                          const float* __restrict__ amask,
                          u16* __restrict__ Xbf, u16* __restrict__ DWbf, float* __restrict__ M8){
  int blk = blockIdx.x; int b = blk>>11; int s = blk&2047;
  int c0 = threadIdx.x*4;
  if (threadIdx.x == 0) M8[blk] = amask[blk] * LOG2E;
  size_t base = (size_t)blk*C_IN + c0;
  float4 xc = *(const float4*)(X + base);
  *(ushort4*)(Xbf + base) = make_ushort4(f2b(xc.x), f2b(xc.y), f2b(xc.z), f2b(xc.w));
  float a0=0.f,a1=0.f,a2=0.f,a3=0.f;
  #pragma unroll
  for (int k=0;k<KK9;k++){
    int ss = s + k - 4;
    if ((unsigned)ss < 2048u){
      float4 xv = *(const float4*)(X + ((size_t)((b<<11)+ss)*C_IN + c0));
      float4 wv = *(const float4*)(dwk + k*C_IN + c0);
      a0 += xv.x*wv.x; a1 += xv.y*wv.y; a2 += xv.z*wv.z; a3 += xv.w*wv.w;
    }
  }
  *(ushort4*)(DWbf + base) = make_ushort4(f2b(a0), f2b(a1), f2b(a2), f2b(a3));
}

// ---------------- 5-way fused projection GEMM: [8192,768]x[768,384] ----------------
// z: 0=Q(-> scaled by SCL) 1=K 2=V(-> transposed Vt) 3=CO 4=KeyConv
__global__ __launch_bounds__(256) void k_gemm5(
    const u16* __restrict__ Xbf, const u16* __restrict__ DWbf,
    const u16* __restrict__ WtQ, const u16* __restrict__ WtK, const u16* __restrict__ WtV,
    const u16* __restrict__ WtCO, const u16* __restrict__ WtPW,
    const float* __restrict__ bq, const float* __restrict__ bk_, const float* __restrict__ bv,
    const float* __restrict__ bco, const float* __restrict__ bcv,
    u16* __restrict__ Qo, u16* __restrict__ Ko, u16* __restrict__ Vt,
    u16* __restrict__ COo, u16* __restrict__ KCo)
{
  __shared__ char smem[32768];
  int tid = threadIdx.x, l = tid&63, w = tid>>6;
  int g = l>>4, c = l&15;
  int wr = w>>1, wc = w&1;
  int mt = blockIdx.x, nt = blockIdx.y, z = blockIdx.z;
  const u16* A = (z==4) ? DWbf : Xbf;
  const u16* B = (z==0)?WtQ:(z==1)?WtK:(z==2)?WtV:(z==3)?WtCO:WtPW;
  const float* bias = (z==0)?bq:(z==1)?bk_:(z==2)?bv:(z==3)?bco:bcv;
  float oscale = (z==0) ? SCL : 1.0f;

  char* La = smem; char* Lb = smem + 16384;
  int m0 = mt*128, n0 = nt*128;

  f32x4 zero = {0.f,0.f,0.f,0.f};
  f32x4 acc[4][4];
  #pragma unroll
  for (int i=0;i<4;i++)
    #pragma unroll
    for (int j=0;j<4;j++) acc[i][j] = zero;

  int rr = w*8 + (l>>3);
  int ch = l&7;

  for (int kt=0; kt<12; kt++){
    #pragma unroll
    for (int i=0;i<4;i++){
      int row = i*32 + rr;
      int sc = ch ^ (row&7);
      gload_lds16(A + (size_t)(m0+row)*C_IN + kt*64 + sc*8, La + i*4096 + w*1024);
      gload_lds16(B + (size_t)(n0+row)*C_IN + kt*64 + sc*8, Lb + i*4096 + w*1024);
    }
    __syncthreads();
    bf16x8 af[4][2], bfr[4][2];
    #pragma unroll
    for (int mi=0;mi<4;mi++){
      int row = wr*64 + mi*16 + c;
      #pragma unroll
      for (int kk=0;kk<2;kk++){
        int sw = (kk*4+g) ^ (row&7);
        af[mi][kk] = *(const bf16x8*)(La + row*128 + sw*16);
      }
    }
    #pragma unroll
    for (int ni=0;ni<4;ni++){
      int row = wc*64 + ni*16 + c;
      #pragma unroll
      for (int kk=0;kk<2;kk++){
        int sw = (kk*4+g) ^ (row&7);
        bfr[ni][kk] = *(const bf16x8*)(Lb + row*128 + sw*16);
      }
    }
    #pragma unroll
    for (int kk=0;kk<2;kk++)
      #pragma unroll
      for (int mi=0;mi<4;mi++)
        #pragma unroll
        for (int ni=0;ni<4;ni++)
          acc[mi][ni] = __builtin_amdgcn_mfma_f32_16x16x32_bf16(af[mi][kk], bfr[ni][kk], acc[mi][ni], 0,0,0);
    __syncthreads();
  }

  if (z == 2){
    #pragma unroll
    for (int ni=0;ni<4;ni++){
      int col = n0 + wc*64 + ni*16 + c;
      float bvv = bias[col];
      int hh = col>>6, d = col&63;
      #pragma unroll
      for (int mi=0;mi<4;mi++){
        int rowg = m0 + wr*64 + mi*16 + g*4;
        int bb = rowg>>11, s = rowg&2047;
        ushort4 pk = make_ushort4(f2b(acc[mi][ni][0] + bvv), f2b(acc[mi][ni][1] + bvv),
                                  f2b(acc[mi][ni][2] + bvv), f2b(acc[mi][ni][3] + bvv));
        *(ushort4*)(Vt + ((size_t)((bb*NH+hh)*HD + d))*BSEQ + s) = pk;
      }
    }
  } else {
    u16* O = (z==0)?Qo:(z==1)?Ko:(z==3)?COo:KCo;
    #pragma unroll
    for (int ni=0;ni<4;ni++){
      int col = n0 + wc*64 + ni*16 + c;
      float bvv = bias[col];
      #pragma unroll
      for (int mi=0;mi<4;mi++)
        #pragma unroll
        for (int r=0;r<4;r++){
          int rowg = m0 + wr*64 + mi*16 + g*4 + r;
          O[(size_t)rowg*AHS + col] = f2b((acc[mi][ni][r] + bvv) * oscale);
        }
    }
  }
}

// ---------------- span-kernel GEMM + softmax: CKP[8192][54] ----------------
__global__ __launch_bounds__(256) void k_ckgemm(const u16* __restrict__ QS, const u16* __restrict__ KCb,
    const u16* __restrict__ WckT, const float* __restrict__ bck, float* __restrict__ ckp)
{
  __shared__ char smem[73728];   // W 48K | CA 24K
  int tid = threadIdx.x, l = tid&63, w = tid>>6;
  int g = l>>4, c = l&15;
  int m0 = blockIdx.x * 32;
  char* Wl = smem;
  char* Al = smem + 49152;

  #pragma unroll
  for (int p=0; p<12; p++){
    int cid = p*256 + tid;
    int row = cid/48, chq = cid - row*48;
    int srow = row < 54 ? row : 53;
    int sch = (chq & ~7) | ((chq ^ row) & 7);
    gload_lds16(WckT + (size_t)srow*AHS + sch*8, Wl + p*4096 + w*1024);
  }
  #pragma unroll
  for (int p=0; p<6; p++){
    int cid = p*256 + tid;
    int row = cid/48, chq = cid - row*48;
    bf16x8 qv = *(const bf16x8*)(QS  + (size_t)(m0+row)*AHS + chq*8);
    bf16x8 kv = *(const bf16x8*)(KCb + (size_t)(m0+row)*AHS + chq*8);
    union { unsigned u[4]; bf16x8 v; } uu;
    #pragma unroll
    for (int j=0;j<4;j++){
      float lo = b2f((u16)qv[2*j])   * b2f((u16)kv[2*j])   * INVSCL;
      float hi = b2f((u16)qv[2*j+1]) * b2f((u16)kv[2*j+1]) * INVSCL;
      uu.u[j] = cvtpk_bf16(lo, hi);
    }
    int sch = (chq & ~7) | ((chq ^ row) & 7);
    *(bf16x8*)(Al + row*768 + sch*16) = uu.v;
  }
  __syncthreads();

  f32x4 zero = {0.f,0.f,0.f,0.f};
  f32x4 acc[2] = {zero, zero};
  #pragma unroll
  for (int ks=0; ks<12; ks++){
    bf16x8 af[2], bfr;
    #pragma unroll
    for (int mi=0;mi<2;mi++){
      int row = mi*16 + c;
      int chq = ks*4 + g;
      int sch = (chq & ~7) | ((chq ^ row) & 7);
      af[mi] = *(const bf16x8*)(Al + row*768 + sch*16);
    }
    {
      int row = w*16 + c;
      int chq = ks*4 + g;
      int sch = (chq & ~7) | ((chq ^ row) & 7);
      bfr = *(const bf16x8*)(Wl + row*768 + sch*16);
    }
    acc[0] = __builtin_amdgcn_mfma_f32_16x16x32_bf16(af[0], bfr, acc[0], 0,0,0);
    acc[1] = __builtin_amdgcn_mfma_f32_16x16x32_bf16(af[1], bfr, acc[1], 0,0,0);
  }

  float* LG = (float*)Al;
  __syncthreads();
  int n = w*16 + c;
  float bb = (n < 54) ? bck[n] : 0.f;
  #pragma unroll
  for (int mi=0;mi<2;mi++)
    #pragma unroll
    for (int r=0;r<4;r++){
      int m = mi*16 + g*4 + r;
      LG[m*64 + n] = acc[mi][r] + bb;
    }
  __syncthreads();
  if (tid < 192){
    int row = tid/6, hh = tid - (tid/6)*6;
    float lg9[9];
    float mx = -1e30f;
    #pragma unroll
    for (int j=0;j<9;j++){ lg9[j] = LG[row*64 + hh*9 + j]; mx = fmaxf(mx, lg9[j]); }
    float s = 0.f;
    #pragma unroll
    for (int j=0;j<9;j++){ lg9[j] = __expf(lg9[j]-mx); s += lg9[j]; }
    float inv = 1.f/s;
    #pragma unroll
    for (int j=0;j<9;j++) ckp[(size_t)(m0+row)*(NH*KK9) + hh*9 + j] = lg9[j]*inv;
  }
}

// ---------------- fused tail: dynamic-conv output + attn k-split combine ----------------
// writes BOTH halves of out[:, :, 0:768]. 2048 blocks x 384 thr, 4 rows/block.
__global__ __launch_bounds__(384) void k_convout(const u16* __restrict__ CO, const float* __restrict__ ckp,
                                                 const float* __restrict__ OP, const float* __restrict__ LS,
                                                 const float* __restrict__ hmask, float* __restrict__ out)
{
  int tid = threadIdx.x;
  int pos = tid/96, lane96 = tid - pos*96;
  int sIdx = blockIdx.x*4 + pos;
  int b = sIdx>>11, s = sIdx&2047;
  int cc = lane96*4, h = cc>>6;
  __shared__ float ck[4][NH*KK9];
  if (lane96 < NH*KK9) ck[pos][lane96] = ckp[(size_t)sIdx*(NH*KK9) + lane96];
  __syncthreads();
  // conv half -> out[:, 384+cc]
  float a0=0.f,a1=0.f,a2=0.f,a3=0.f;
  #pragma unroll
  for (int k=0;k<KK9;k++){
    int ss = s + k - 4;
    if ((unsigned)ss < 2048u){
      ushort4 v = *(const ushort4*)(CO + ((size_t)((b<<11)+ss)*AHS + cc));
      float wk = ck[pos][h*KK9+k];
      a0 += b2f(v.x)*wk; a1 += b2f(v.y)*wk; a2 += b2f(v.z)*wk; a3 += b2f(v.w)*wk;
    }
  }
  *(float4*)(out + (size_t)sIdx*(2*AHS) + AHS + cc) = make_float4(a0,a1,a2,a3);
  // attn half (combine k-split) -> out[:, cc]
  float4 v0 = *(const float4*)(OP + (size_t)sIdx*AHS + cc);
  float4 v1 = *(const float4*)(OP + ((size_t)(MTOT + sIdx))*AHS + cc);
  float lsum = LS[(size_t)sIdx*NH + h] + LS[((size_t)(MTOT + sIdx))*NH + h];
  float sc = hmask[h] / lsum;
  *(float4*)(out + (size_t)sIdx*(2*AHS) + cc) =
      make_float4((v0.x+v1.x)*sc, (v0.y+v1.y)*sc, (v0.z+v1.z)*sc, (v0.w+v1.w)*sc);
}

// ---------------- flash attention (k-split x2, 16q/wave) — R6 structure verbatim ----------------
// 1536 blocks: (bh, qt, half). 4 waves x 16 q-rows; LDS dbuf K/V over 16 KV-iters.
// Swapped QK^T; in-register P; row-sums via MFMA-with-ones. f32 partials. VGPR ~64, no spill.
__global__ __launch_bounds__(256) void k_attn(const u16* __restrict__ QS, const u16* __restrict__ Kb,
    const u16* __restrict__ Vt, const float* __restrict__ M8,
    float* __restrict__ OP, float* __restrict__ LS)
{
  __shared__ char smem[32768]; // K dbuf 16K | V dbuf 16K
  int tid = threadIdx.x, l = tid&63, w = tid>>6;
  int g = l>>4, c = l&15;
  // bijective XCD swizzle over 1536 blocks; 192/XCD -> 3 bh per XCD
  int n = blockIdx.x;
  int sw = (n & 7) * 192 + (n >> 3);
  int bh = sw >> 6, rem = sw & 63;
  int qt = rem >> 1, half = rem & 1;
  int b = bh/NH, h = bh - b*NH;

  char* Kls = smem;
  char* Vls = smem + 16384;

  int q0 = qt*64 + w*16;
  bf16x8 aq[2];
  #pragma unroll
  for (int kk=0;kk<2;kk++)
    aq[kk] = *(const bf16x8*)(QS + (size_t)(b*BSEQ + q0 + c)*AHS + h*HD + kk*32 + g*8);

  const bf16x8 ONES = {(short)0x3F80,(short)0x3F80,(short)0x3F80,(short)0x3F80,
                       (short)0x3F80,(short)0x3F80,(short)0x3F80,(short)0x3F80};

  f32x4 o[4];
  #pragma unroll
  for (int j=0;j<4;j++) o[j] = f32x4{0.f,0.f,0.f,0.f};
  f32x4 o_s = {0.f,0.f,0.f,0.f};

  int rr = w*8 + (l>>3), ch = l&7;
  const u16* Kbase = Kb + ((size_t)b*BSEQ + half*1024)*AHS + h*HD;
  const u16* Vbase = Vt + (size_t)bh*HD*BSEQ + half*1024;
  const float* mrow = M8 + b*BSEQ + half*1024;

  #pragma unroll
  for (int i=0;i<2;i++){
    int row = i*32 + rr; int sc = ch ^ (row&7);
    gload_lds16(Kbase + (size_t)row*AHS + sc*8, Kls + i*4096 + w*1024);
    gload_lds16(Vbase + (size_t)row*BSEQ + sc*8, Vls + i*4096 + w*1024);
  }
  __syncthreads();

  for (int t=0;t<16;t++){
    int p = t&1;
    if (t < 15){
      int tn = t+1;
      #pragma unroll
      for (int i=0;i<2;i++){
        int row = i*32 + rr; int sc = ch ^ (row&7);
        gload_lds16(Kbase + (size_t)(tn*64 + row)*AHS + sc*8, Kls + (p^1)*8192 + i*4096 + w*1024);
        gload_lds16(Vbase + (size_t)row*BSEQ + tn*64 + sc*8,  Vls + (p^1)*8192 + i*4096 + w*1024);
      }
    }
    bf16x8 kf[4][2];
    #pragma unroll
    for (int ka=0;ka<4;ka++){
      int row = ka*16 + c;
      #pragma unroll
      for (int kk=0;kk<2;kk++){
        int swz = (kk*4+g) ^ (row&7);
        kf[ka][kk] = *(const bf16x8*)(Kls + p*8192 + row*128 + swz*16);
      }
    }
    f32x4 s4[4];
    #pragma unroll
    for (int ka=0;ka<4;ka++){
      float4 mk = *(const float4*)(mrow + t*64 + ka*16 + g*4);
      s4[ka][0] = mk.x; s4[ka][1] = mk.y; s4[ka][2] = mk.z; s4[ka][3] = mk.w;
    }
    __builtin_amdgcn_s_setprio(1);
    #pragma unroll
    for (int ka=0;ka<4;ka++){
      s4[ka] = __builtin_amdgcn_mfma_f32_16x16x32_bf16(kf[ka][0], aq[0], s4[ka], 0,0,0);
      s4[ka] = __builtin_amdgcn_mfma_f32_16x16x32_bf16(kf[ka][1], aq[1], s4[ka], 0,0,0);
    }
    __builtin_amdgcn_s_setprio(0);
    unsigned pkw[4][2];
    #pragma unroll
    for (int ka=0;ka<4;ka++){
      float p0 = exp2f(s4[ka][0]);
      float p1 = exp2f(s4[ka][1]);
      float p2 = exp2f(s4[ka][2]);
      float p3 = exp2f(s4[ka][3]);
      pkw[ka][0] = cvtpk_bf16(p0, p1);
      pkw[ka][1] = cvtpk_bf16(p2, p3);
    }
    bf16x8 pa[2];
    #pragma unroll
    for (int kk=0;kk<2;kk++){
      unsigned e0 = pkw[2*kk][0],   e1 = pkw[2*kk][1];
      unsigned o0 = pkw[2*kk+1][0], o1 = pkw[2*kk+1][1];
      asm volatile("v_permlane32_swap_b32 %0, %1" : "+v"(e0), "+v"(o0));
      asm volatile("v_permlane16_swap_b32 %0, %1" : "+v"(e0), "+v"(o0));
      asm volatile("v_permlane32_swap_b32 %0, %1" : "+v"(e1), "+v"(o1));
      asm volatile("v_permlane16_swap_b32 %0, %1" : "+v"(e1), "+v"(o1));
      union { unsigned u[4]; bf16x8 v; } uu;
      uu.u[0] = e0; uu.u[1] = e1; uu.u[2] = o0; uu.u[3] = o1;
      pa[kk] = uu.v;
    }
    bf16x8 vf[4][2];
    #pragma unroll
    for (int di=0;di<4;di++){
      int row = di*16 + c;
      #pragma unroll
      for (int kk=0;kk<2;kk++){
        int swz = (kk*4+g) ^ (row&7);
        vf[di][kk] = *(const bf16x8*)(Vls + p*8192 + row*128 + swz*16);
      }
    }
    __builtin_amdgcn_s_setprio(1);
    #pragma unroll
    for (int kk=0;kk<2;kk++){
      #pragma unroll
      for (int di=0;di<4;di++)
        o[di] = __builtin_amdgcn_mfma_f32_16x16x32_bf16(pa[kk], vf[di][kk], o[di], 0,0,0);
      o_s = __builtin_amdgcn_mfma_f32_16x16x32_bf16(pa[kk], ONES, o_s, 0,0,0);
    }
    __builtin_amdgcn_s_setprio(0);
    __syncthreads();
  }

  // write unnormalized partials; o_s[r] = lsum for q=g*4+r (replicated across c)
  #pragma unroll
  for (int r=0;r<4;r++){
    int rowq = q0 + g*4 + r;
    size_t rbase = (size_t)(half*MTOT + b*BSEQ + rowq);
    if (c == 0) LS[rbase*NH + h] = o_s[r];
    #pragma unroll
    for (int di=0;di<4;di++)
      OP[rbase*AHS + h*HD + di*16 + c] = o[di][r];
  }
}

extern "C" void kernel_launch(void* const* d_in, const int* in_sizes, int n_in,
                              void* d_out, int out_size, void* d_ws, size_t ws_size,
                              hipStream_t stream) {
  (void)in_sizes; (void)n_in; (void)out_size; (void)ws_size;
  const float* X     = (const float*)d_in[0];
  const float* amask = (const float*)d_in[1];
  const float* hmask = (const float*)d_in[2];
  const float* Wq  = (const float*)d_in[3];
  const float* bq  = (const float*)d_in[4];
  const float* Wk  = (const float*)d_in[5];
  const float* bk  = (const float*)d_in[6];
  const float* Wv  = (const float*)d_in[7];
  const float* bv  = (const float*)d_in[8];
  const float* dwk = (const float*)d_in[9];
  const float* pw  = (const float*)d_in[10];
  const float* cb  = (const float*)d_in[11];
  const float* Wck = (const float*)d_in[12];
  const float* bck = (const float*)d_in[13];
  const float* Wco = (const float*)d_in[14];
  const float* bco = (const float*)d_in[15];
  float* out = (float*)d_out;

  char* p = (char*)d_ws;
  u16* XBF  = (u16*)p; p += (size_t)MTOT*C_IN*2;
  u16* DWBF = (u16*)p; p += (size_t)MTOT*C_IN*2;
  u16* WTQ  = (u16*)p; p += (size_t)C_IN*AHS*2;
  u16* WTK  = (u16*)p; p += (size_t)C_IN*AHS*2;
  u16* WTV  = (u16*)p; p += (size_t)C_IN*AHS*2;
  u16* WTCO = (u16*)p; p += (size_t)C_IN*AHS*2;
  u16* WTPW = (u16*)p; p += (size_t)C_IN*AHS*2;
  u16* WCKT = (u16*)p; p += (size_t)(NH*KK9)*AHS*2;
  u16* QS   = (u16*)p; p += (size_t)MTOT*AHS*2;
  u16* KB   = (u16*)p; p += (size_t)MTOT*AHS*2;
  u16* COB  = (u16*)p; p += (size_t)MTOT*AHS*2;
  u16* KCB  = (u16*)p; p += (size_t)MTOT*AHS*2;
  u16* VT   = (u16*)p; p += (size_t)MTOT*AHS*2;
  float* CKP = (float*)p; p += (size_t)MTOT*(NH*KK9)*4;
  float* M8  = (float*)p; p += (size_t)MTOT*4;

  // attn partials alias buffers dead after k_gemm5:
  float* OP = (float*)XBF;   // 2 * 8192*384*4B == XBF+DWBF region (25.2MB)
  float* LS = (float*)WTQ;   // 2 * 8192*6*4B = 393KB < WTQ

  dim3 tb(32,8);
  k_transpose_cast5<<<dim3(24,12,5),tb,0,stream>>>(Wq, Wk, Wv, Wco, pw, WTQ, WTK, WTV, WTCO, WTPW);
  k_transpose_cast<<<dim3(12,2), tb,0,stream>>>(Wck, WCKT, AHS, NH*KK9);

  k_prep_x<<<MTOT,192,0,stream>>>(X, dwk, amask, XBF, DWBF, M8);

  k_gemm5<<<dim3(64,3,5),256,0,stream>>>(XBF, DWBF, WTQ, WTK, WTV, WTCO, WTPW,
                                         bq, bk, bv, bco, cb,
                                         QS, KB, VT, COB, KCB);

  k_ckgemm<<<256,256,0,stream>>>(QS, KCB, WCKT, bck, CKP);
  k_attn<<<1536,256,0,stream>>>(QS, KB, VT, M8, OP, LS);
  k_convout<<<2048,384,0,stream>>>(COB, CKP, OP, LS, hmask, out);
}

// Round 12
// 158.545 us; speedup vs baseline: 1.5591x; 1.0015x over previous
//
#include <hip/hip_runtime.h>
#include <hip/hip_bf16.h>
#include <stdint.h>

typedef unsigned short u16;
typedef short bf16x8 __attribute__((ext_vector_type(8)));
typedef float f32x4 __attribute__((ext_vector_type(4)));

#define C_IN 768
#define AHS 384
#define NH 6
#define HD 64
#define KK9 9
#define BSEQ 2048
#define MTOT 8192

__device__ __forceinline__ float b2f(u16 u){
  union { unsigned u; float f; } v; v.u = ((unsigned)u) << 16; return v.f;
}
__device__ __forceinline__ u16 f2b(float f){
  union { float f; unsigned u; } v; v.f = f;
  unsigned r = (v.u + 0x7FFFu + ((v.u >> 16) & 1u)) >> 16;
  return (u16)r;
}
__device__ __forceinline__ void gload_lds16(const void* g, void* l){
  __builtin_amdgcn_global_load_lds((const __attribute__((address_space(1))) unsigned int*)g,
                                   (__attribute__((address_space(3))) unsigned int*)l, 16, 0, 0);
}
__device__ __forceinline__ unsigned cvtpk_bf16(float lo, float hi){
  unsigned w;
  asm("v_cvt_pk_bf16_f32 %0, %1, %2" : "=v"(w) : "v"(lo), "v"(hi));
  return w;
}

#define SCL 0.18033688011112042f   // 0.125 * log2(e)
#define INVSCL 5.545177444479562f  // 8 * ln(2)
#define LOG2E 1.4426950408889634f

// ---------------- transpose + cast f32[R][C] -> bf16[C][R], 6 weights fused ----------------
__global__ void k_transpose_cast6(const float* __restrict__ s0, const float* __restrict__ s1,
                                  const float* __restrict__ s2, const float* __restrict__ s3,
                                  const float* __restrict__ s4, const float* __restrict__ s5,
                                  u16* __restrict__ d0, u16* __restrict__ d1, u16* __restrict__ d2,
                                  u16* __restrict__ d3, u16* __restrict__ d4, u16* __restrict__ d5){
  __shared__ float t[32][33];
  int z = blockIdx.z;
  const float* src = (z==0)?s0:(z==1)?s1:(z==2)?s2:(z==3)?s3:(z==4)?s4:s5;
  u16* dst = (z==0)?d0:(z==1)?d1:(z==2)?d2:(z==3)?d3:(z==4)?d4:d5;
  int R = (z<5) ? C_IN : AHS;
  int C = (z<5) ? AHS : (NH*KK9);
  int r0 = blockIdx.x*32, c0 = blockIdx.y*32;
  if (r0 >= R || c0 >= C) return;
  int tx = threadIdx.x, ty = threadIdx.y;
  #pragma unroll
  for (int j=0;j<4;j++){
    int r = r0 + ty + j*8, c = c0 + tx;
    t[ty+j*8][tx] = (r<R && c<C) ? src[(size_t)r*C + c] : 0.f;
  }
  __syncthreads();
  #pragma unroll
  for (int j=0;j<4;j++){
    int c = c0 + ty + j*8, r = r0 + tx;
    if (r<R && c<C) dst[(size_t)c*R + r] = f2b(t[tx][ty+j*8]);
  }
}

// ---------------- X cast + depthwise conv (SAME), plus M8 = amask*log2e ----------------
__global__ __launch_bounds__(192) void k_prep_x(const float* __restrict__ X, const float* __restrict__ dwk,
                          const float* __restrict__ amask,
                          u16* __restrict__ Xbf, u16* __restrict__ DWbf, float* __restrict__ M8){
  int blk = blockIdx.x; int b = blk>>11; int s = blk&2047;
  int c0 = threadIdx.x*4;
  if (threadIdx.x == 0) M8[blk] = amask[blk] * LOG2E;
  size_t base = (size_t)blk*C_IN + c0;
  float4 xc = *(const float4*)(X + base);
  *(ushort4*)(Xbf + base) = make_ushort4(f2b(xc.x), f2b(xc.y), f2b(xc.z), f2b(xc.w));
  float a0=0.f,a1=0.f,a2=0.f,a3=0.f;
  #pragma unroll
  for (int k=0;k<KK9;k++){
    int ss = s + k - 4;
    if ((unsigned)ss < 2048u){
      float4 xv = *(const float4*)(X + ((size_t)((b<<11)+ss)*C_IN + c0));
      float4 wv = *(const float4*)(dwk + k*C_IN + c0);
      a0 += xv.x*wv.x; a1 += xv.y*wv.y; a2 += xv.z*wv.z; a3 += xv.w*wv.w;
    }
  }
  *(ushort4*)(DWbf + base) = make_ushort4(f2b(a0), f2b(a1), f2b(a2), f2b(a3));
}

// ---------------- 5-way fused projection GEMM: [8192,768]x[768,384] ----------------
// z: 0=Q(-> scaled by SCL) 1=K 2=V(-> transposed Vt) 3=CO 4=KeyConv
__global__ __launch_bounds__(256) void k_gemm5(
    const u16* __restrict__ Xbf, const u16* __restrict__ DWbf,
    const u16* __restrict__ WtQ, const u16* __restrict__ WtK, const u16* __restrict__ WtV,
    const u16* __restrict__ WtCO, const u16* __restrict__ WtPW,
    const float* __restrict__ bq, const float* __restrict__ bk_, const float* __restrict__ bv,
    const float* __restrict__ bco, const float* __restrict__ bcv,
    u16* __restrict__ Qo, u16* __restrict__ Ko, u16* __restrict__ Vt,
    u16* __restrict__ COo, u16* __restrict__ KCo)
{
  __shared__ char smem[32768];
  int tid = threadIdx.x, l = tid&63, w = tid>>6;
  int g = l>>4, c = l&15;
  int wr = w>>1, wc = w&1;
  int mt = blockIdx.x, nt = blockIdx.y, z = blockIdx.z;
  const u16* A = (z==4) ? DWbf : Xbf;
  const u16* B = (z==0)?WtQ:(z==1)?WtK:(z==2)?WtV:(z==3)?WtCO:WtPW;
  const float* bias = (z==0)?bq:(z==1)?bk_:(z==2)?bv:(z==3)?bco:bcv;
  float oscale = (z==0) ? SCL : 1.0f;

  char* La = smem; char* Lb = smem + 16384;
  int m0 = mt*128, n0 = nt*128;

  f32x4 zero = {0.f,0.f,0.f,0.f};
  f32x4 acc[4][4];
  #pragma unroll
  for (int i=0;i<4;i++)
    #pragma unroll
    for (int j=0;j<4;j++) acc[i][j] = zero;

  int rr = w*8 + (l>>3);
  int ch = l&7;

  for (int kt=0; kt<12; kt++){
    #pragma unroll
    for (int i=0;i<4;i++){
      int row = i*32 + rr;
      int sc = ch ^ (row&7);
      gload_lds16(A + (size_t)(m0+row)*C_IN + kt*64 + sc*8, La + i*4096 + w*1024);
      gload_lds16(B + (size_t)(n0+row)*C_IN + kt*64 + sc*8, Lb + i*4096 + w*1024);
    }
    __syncthreads();
    bf16x8 af[4][2], bfr[4][2];
    #pragma unroll
    for (int mi=0;mi<4;mi++){
      int row = wr*64 + mi*16 + c;
      #pragma unroll
      for (int kk=0;kk<2;kk++){
        int sw = (kk*4+g) ^ (row&7);
        af[mi][kk] = *(const bf16x8*)(La + row*128 + sw*16);
      }
    }
    #pragma unroll
    for (int ni=0;ni<4;ni++){
      int row = wc*64 + ni*16 + c;
      #pragma unroll
      for (int kk=0;kk<2;kk++){
        int sw = (kk*4+g) ^ (row&7);
        bfr[ni][kk] = *(const bf16x8*)(Lb + row*128 + sw*16);
      }
    }
    #pragma unroll
    for (int kk=0;kk<2;kk++)
      #pragma unroll
      for (int mi=0;mi<4;mi++)
        #pragma unroll
        for (int ni=0;ni<4;ni++)
          acc[mi][ni] = __builtin_amdgcn_mfma_f32_16x16x32_bf16(af[mi][kk], bfr[ni][kk], acc[mi][ni], 0,0,0);
    __syncthreads();
  }

  if (z == 2){
    #pragma unroll
    for (int ni=0;ni<4;ni++){
      int col = n0 + wc*64 + ni*16 + c;
      float bvv = bias[col];
      int hh = col>>6, d = col&63;
      #pragma unroll
      for (int mi=0;mi<4;mi++){
        int rowg = m0 + wr*64 + mi*16 + g*4;
        int bb = rowg>>11, s = rowg&2047;
        ushort4 pk = make_ushort4(f2b(acc[mi][ni][0] + bvv), f2b(acc[mi][ni][1] + bvv),
                                  f2b(acc[mi][ni][2] + bvv), f2b(acc[mi][ni][3] + bvv));
        *(ushort4*)(Vt + ((size_t)((bb*NH+hh)*HD + d))*BSEQ + s) = pk;
      }
    }
  } else {
    u16* O = (z==0)?Qo:(z==1)?Ko:(z==3)?COo:KCo;
    #pragma unroll
    for (int ni=0;ni<4;ni++){
      int col = n0 + wc*64 + ni*16 + c;
      float bvv = bias[col];
      #pragma unroll
      for (int mi=0;mi<4;mi++)
        #pragma unroll
        for (int r=0;r<4;r++){
          int rowg = m0 + wr*64 + mi*16 + g*4 + r;
          O[(size_t)rowg*AHS + col] = f2b((acc[mi][ni][r] + bvv) * oscale);
        }
    }
  }
}

// ---------------- span-kernel GEMM + softmax: CKP[8192][54] ----------------
__global__ __launch_bounds__(256) void k_ckgemm(const u16* __restrict__ QS, const u16* __restrict__ KCb,
    const u16* __restrict__ WckT, const float* __restrict__ bck, float* __restrict__ ckp)
{
  __shared__ char smem[73728];   // W 48K | CA 24K
  int tid = threadIdx.x, l = tid&63, w = tid>>6;
  int g = l>>4, c = l&15;
  int m0 = blockIdx.x * 32;
  char* Wl = smem;
  char* Al = smem + 49152;

  #pragma unroll
  for (int p=0; p<12; p++){
    int cid = p*256 + tid;
    int row = cid/48, chq = cid - row*48;
    int srow = row < 54 ? row : 53;
    int sch = (chq & ~7) | ((chq ^ row) & 7);
    gload_lds16(WckT + (size_t)srow*AHS + sch*8, Wl + p*4096 + w*1024);
  }
  #pragma unroll
  for (int p=0; p<6; p++){
    int cid = p*256 + tid;
    int row = cid/48, chq = cid - row*48;
    bf16x8 qv = *(const bf16x8*)(QS  + (size_t)(m0+row)*AHS + chq*8);
    bf16x8 kv = *(const bf16x8*)(KCb + (size_t)(m0+row)*AHS + chq*8);
    union { unsigned u[4]; bf16x8 v; } uu;
    #pragma unroll
    for (int j=0;j<4;j++){
      float lo = b2f((u16)qv[2*j])   * b2f((u16)kv[2*j])   * INVSCL;
      float hi = b2f((u16)qv[2*j+1]) * b2f((u16)kv[2*j+1]) * INVSCL;
      uu.u[j] = cvtpk_bf16(lo, hi);
    }
    int sch = (chq & ~7) | ((chq ^ row) & 7);
    *(bf16x8*)(Al + row*768 + sch*16) = uu.v;
  }
  __syncthreads();

  f32x4 zero = {0.f,0.f,0.f,0.f};
  f32x4 acc[2] = {zero, zero};
  #pragma unroll
  for (int ks=0; ks<12; ks++){
    bf16x8 af[2], bfr;
    #pragma unroll
    for (int mi=0;mi<2;mi++){
      int row = mi*16 + c;
      int chq = ks*4 + g;
      int sch = (chq & ~7) | ((chq ^ row) & 7);
      af[mi] = *(const bf16x8*)(Al + row*768 + sch*16);
    }
    {
      int row = w*16 + c;
      int chq = ks*4 + g;
      int sch = (chq & ~7) | ((chq ^ row) & 7);
      bfr = *(const bf16x8*)(Wl + row*768 + sch*16);
    }
    acc[0] = __builtin_amdgcn_mfma_f32_16x16x32_bf16(af[0], bfr, acc[0], 0,0,0);
    acc[1] = __builtin_amdgcn_mfma_f32_16x16x32_bf16(af[1], bfr, acc[1], 0,0,0);
  }

  float* LG = (float*)Al;
  __syncthreads();
  int n = w*16 + c;
  float bb = (n < 54) ? bck[n] : 0.f;
  #pragma unroll
  for (int mi=0;mi<2;mi++)
    #pragma unroll
    for (int r=0;r<4;r++){
      int m = mi*16 + g*4 + r;
      LG[m*64 + n] = acc[mi][r] + bb;
    }
  __syncthreads();
  if (tid < 192){
    int row = tid/6, hh = tid - (tid/6)*6;
    float lg9[9];
    float mx = -1e30f;
    #pragma unroll
    for (int j=0;j<9;j++){ lg9[j] = LG[row*64 + hh*9 + j]; mx = fmaxf(mx, lg9[j]); }
    float s = 0.f;
    #pragma unroll
    for (int j=0;j<9;j++){ lg9[j] = __expf(lg9[j]-mx); s += lg9[j]; }
    float inv = 1.f/s;
    #pragma unroll
    for (int j=0;j<9;j++) ckp[(size_t)(m0+row)*(NH*KK9) + hh*9 + j] = lg9[j]*inv;
  }
}

// ---------------- fused tail: dynamic-conv output + attn 4-way k-split combine ----------------
// OPb32: [split][MTOT/2 row-pairs][AHS] u32; each u32 = (bf16 row_even, bf16 row_odd).
__global__ __launch_bounds__(384) void k_convout(const u16* __restrict__ CO, const float* __restrict__ ckp,
                                                 const unsigned* __restrict__ OPb32, const float* __restrict__ LS,
                                                 const float* __restrict__ hmask, float* __restrict__ out)
{
  int tid = threadIdx.x;
  int pos = tid/96, lane96 = tid - pos*96;
  int sIdx = blockIdx.x*4 + pos;
  int b = sIdx>>11, s = sIdx&2047;
  int cc = lane96*4, h = cc>>6;
  __shared__ float ck[4][NH*KK9];
  if (lane96 < NH*KK9) ck[pos][lane96] = ckp[(size_t)sIdx*(NH*KK9) + lane96];
  __syncthreads();
  // conv half -> out[:, 384+cc]
  float a0=0.f,a1=0.f,a2=0.f,a3=0.f;
  #pragma unroll
  for (int k=0;k<KK9;k++){
    int ss = s + k - 4;
    if ((unsigned)ss < 2048u){
      ushort4 v = *(const ushort4*)(CO + ((size_t)((b<<11)+ss)*AHS + cc));
      float wk = ck[pos][h*KK9+k];
      a0 += b2f(v.x)*wk; a1 += b2f(v.y)*wk; a2 += b2f(v.z)*wk; a3 += b2f(v.w)*wk;
    }
  }
  *(float4*)(out + (size_t)sIdx*(2*AHS) + AHS + cc) = make_float4(a0,a1,a2,a3);
  // attn half (combine 4 k-split quarters) -> out[:, cc]
  int pr = sIdx>>1, sub = sIdx&1;
  float o0=0.f,o1=0.f,o2=0.f,o3=0.f, lsum=0.f;
  #pragma unroll
  for (int sp=0; sp<4; sp++){
    uint4 w4 = *(const uint4*)(OPb32 + ((size_t)(sp*(MTOT/2) + pr))*AHS + cc);
    o0 += b2f((u16)(sub ? (w4.x>>16) : (w4.x&0xFFFF)));
    o1 += b2f((u16)(sub ? (w4.y>>16) : (w4.y&0xFFFF)));
    o2 += b2f((u16)(sub ? (w4.z>>16) : (w4.z&0xFFFF)));
    o3 += b2f((u16)(sub ? (w4.w>>16) : (w4.w&0xFFFF)));
    lsum += LS[((size_t)(sp*MTOT + sIdx))*NH + h];
  }
  float sc = hmask[h] / lsum;
  *(float4*)(out + (size_t)sIdx*(2*AHS) + cc) = make_float4(o0*sc, o1*sc, o2*sc, o3*sc);
}

// ---------------- flash attention (k-split x4, KVBLK=32, 16q/wave) ----------------
// 3072 blocks: (bh, qt, quarter). 4 waves x 16 q-rows; LDS 16KB (K 4K dbuf + V 4K dbuf)
// -> 8 blocks/CU (wave-capped, 100% occupancy). Swapped QK^T; in-register P;
// row-sums via MFMA-with-ones. Row-pair-packed bf16 partials (64B write segments).
__global__ __launch_bounds__(256) void k_attn(const u16* __restrict__ QS, const u16* __restrict__ Kb,
    const u16* __restrict__ Vt, const float* __restrict__ M8,
    unsigned* __restrict__ OPb32, float* __restrict__ LS)
{
  __shared__ char smem[16384]; // K dbuf 2x4K | V dbuf 2x4K
  int tid = threadIdx.x, l = tid&63, w = tid>>6;
  int g = l>>4, c = l&15;
  // bijective XCD swizzle over 3072 blocks: 384/XCD = 3 bh per XCD
  int n = blockIdx.x;
  int sw = (n & 7) * 384 + (n >> 3);
  int bh = sw >> 7, rem = sw & 127;
  int qt = rem >> 2, qr = rem & 3;
  int b = bh/NH, h = bh - b*NH;

  char* Kls = smem;            // 2 x 4096
  char* Vls = smem + 8192;     // 2 x 4096

  int q0 = qt*64 + w*16;
  bf16x8 aq[2];
  #pragma unroll
  for (int kk=0;kk<2;kk++)
    aq[kk] = *(const bf16x8*)(QS + (size_t)(b*BSEQ + q0 + c)*AHS + h*HD + kk*32 + g*8);

  const bf16x8 ONES = {(short)0x3F80,(short)0x3F80,(short)0x3F80,(short)0x3F80,
                       (short)0x3F80,(short)0x3F80,(short)0x3F80,(short)0x3F80};

  f32x4 o[4];
  #pragma unroll
  for (int j=0;j<4;j++) o[j] = f32x4{0.f,0.f,0.f,0.f};
  f32x4 o_s = {0.f,0.f,0.f,0.f};

  // K staging coords: row rk = tid>>3 (0..31), chunk chk = tid&7 (128B rows)
  int rk = tid>>3, chk = tid&7;
  // V staging coords: row rv = tid>>2 (0..63), chunk cv = tid&3 (64B rows)
  int rv = tid>>2, cv = tid&3;
  const u16* Kbase = Kb + ((size_t)b*BSEQ + qr*512)*AHS + h*HD;
  const u16* Vbase = Vt + (size_t)bh*HD*BSEQ + qr*512;
  const float* mrow = M8 + b*BSEQ + qr*512;

  // prologue: stage t=0 into buffer 0 (one gload each for K and V per thread)
  gload_lds16(Kbase + (size_t)rk*AHS + (chk ^ (rk&7))*8, Kls + w*1024);
  gload_lds16(Vbase + (size_t)rv*BSEQ + (cv ^ (rv&3))*8, Vls + w*1024);
  __syncthreads();

  for (int t=0;t<16;t++){
    int p = t&1;
    if (t < 15){
      int tn = t+1;
      gload_lds16(Kbase + (size_t)(tn*32 + rk)*AHS + (chk ^ (rk&7))*8, Kls + (p^1)*4096 + w*1024);
      gload_lds16(Vbase + (size_t)rv*BSEQ + tn*32 + (cv ^ (rv&3))*8,   Vls + (p^1)*4096 + w*1024);
    }
    // K fragments (A-operand): K[k=ka*16+c][d=kk*32+g*8+j], rows 128B
    bf16x8 kf[2][2];
    #pragma unroll
    for (int ka=0;ka<2;ka++){
      int row = ka*16 + c;
      #pragma unroll
      for (int kk=0;kk<2;kk++){
        int swz = (kk*4+g) ^ (row&7);
        kf[ka][kk] = *(const bf16x8*)(Kls + p*4096 + row*128 + swz*16);
      }
    }
    f32x4 s4[2];
    #pragma unroll
    for (int ka=0;ka<2;ka++){
      float4 mk = *(const float4*)(mrow + t*32 + ka*16 + g*4);
      s4[ka][0] = mk.x; s4[ka][1] = mk.y; s4[ka][2] = mk.z; s4[ka][3] = mk.w;
    }
    __builtin_amdgcn_s_setprio(1);
    #pragma unroll
    for (int ka=0;ka<2;ka++){
      s4[ka] = __builtin_amdgcn_mfma_f32_16x16x32_bf16(kf[ka][0], aq[0], s4[ka], 0,0,0);
      s4[ka] = __builtin_amdgcn_mfma_f32_16x16x32_bf16(kf[ka][1], aq[1], s4[ka], 0,0,0);
    }
    __builtin_amdgcn_s_setprio(0);
    unsigned pkw[2][2];
    #pragma unroll
    for (int ka=0;ka<2;ka++){
      float p0 = exp2f(s4[ka][0]);
      float p1 = exp2f(s4[ka][1]);
      float p2 = exp2f(s4[ka][2]);
      float p3 = exp2f(s4[ka][3]);
      pkw[ka][0] = cvtpk_bf16(p0, p1);
      pkw[ka][1] = cvtpk_bf16(p2, p3);
    }
    // assemble PV A-fragment in-register: P[q=c][k=g*8+j] (k-range 32)
    bf16x8 pa;
    {
      unsigned e0 = pkw[0][0], e1 = pkw[0][1];
      unsigned o0 = pkw[1][0], o1 = pkw[1][1];
      asm volatile("v_permlane32_swap_b32 %0, %1" : "+v"(e0), "+v"(o0));
      asm volatile("v_permlane16_swap_b32 %0, %1" : "+v"(e0), "+v"(o0));
      asm volatile("v_permlane32_swap_b32 %0, %1" : "+v"(e1), "+v"(o1));
      asm volatile("v_permlane16_swap_b32 %0, %1" : "+v"(e1), "+v"(o1));
      union { unsigned u[4]; bf16x8 v; } uu;
      uu.u[0] = e0; uu.u[1] = e1; uu.u[2] = o0; uu.u[3] = o1;
      pa = uu.v;
    }
    // V fragments (B-operand): V[s=g*8+j][d=di*16+c], rows 64B (4 chunks, chunk^=row&3)
    bf16x8 vf[4];
    #pragma unroll
    for (int di=0;di<4;di++){
      int row = di*16 + c;
      int swz = g ^ (row&3);
      vf[di] = *(const bf16x8*)(Vls + p*4096 + row*64 + swz*16);
    }
    __builtin_amdgcn_s_setprio(1);
    #pragma unroll
    for (int di=0;di<4;di++)
      o[di] = __builtin_amdgcn_mfma_f32_16x16x32_bf16(pa, vf[di], o[di], 0,0,0);
    o_s = __builtin_amdgcn_mfma_f32_16x16x32_bf16(pa, ONES, o_s, 0,0,0);
    __builtin_amdgcn_s_setprio(0);
    __syncthreads();
  }

  // packed bf16 partials: rows (r, r+1) -> one u32 per (di, lane c)
  #pragma unroll
  for (int r=0;r<4;r+=2){
    int rowq = q0 + g*4 + r;
    size_t rp = (size_t)(qr*(MTOT/2)) + ((size_t)(b*BSEQ + rowq) >> 1);
    if (c == 0){
      LS[((size_t)(qr*MTOT + b*BSEQ + rowq))*NH + h]     = o_s[r];
      LS[((size_t)(qr*MTOT + b*BSEQ + rowq + 1))*NH + h] = o_s[r+1];
    }
    #pragma unroll
    for (int di=0;di<4;di++)
      OPb32[rp*AHS + h*HD + di*16 + c] = cvtpk_bf16(o[di][r], o[di][r+1]);
  }
}

extern "C" void kernel_launch(void* const* d_in, const int* in_sizes, int n_in,
                              void* d_out, int out_size, void* d_ws, size_t ws_size,
                              hipStream_t stream) {
  (void)in_sizes; (void)n_in; (void)out_size; (void)ws_size;
  const float* X     = (const float*)d_in[0];
  const float* amask = (const float*)d_in[1];
  const float* hmask = (const float*)d_in[2];
  const float* Wq  = (const float*)d_in[3];
  const float* bq  = (const float*)d_in[4];
  const float* Wk  = (const float*)d_in[5];
  const float* bk  = (const float*)d_in[6];
  const float* Wv  = (const float*)d_in[7];
  const float* bv  = (const float*)d_in[8];
  const float* dwk = (const float*)d_in[9];
  const float* pw  = (const float*)d_in[10];
  const float* cb  = (const float*)d_in[11];
  const float* Wck = (const float*)d_in[12];
  const float* bck = (const float*)d_in[13];
  const float* Wco = (const float*)d_in[14];
  const float* bco = (const float*)d_in[15];
  float* out = (float*)d_out;

  char* p = (char*)d_ws;
  u16* XBF  = (u16*)p; p += (size_t)MTOT*C_IN*2;
  u16* DWBF = (u16*)p; p += (size_t)MTOT*C_IN*2;
  u16* WTQ  = (u16*)p; p += (size_t)C_IN*AHS*2;
  u16* WTK  = (u16*)p; p += (size_t)C_IN*AHS*2;
  u16* WTV  = (u16*)p; p += (size_t)C_IN*AHS*2;
  u16* WTCO = (u16*)p; p += (size_t)C_IN*AHS*2;
  u16* WTPW = (u16*)p; p += (size_t)C_IN*AHS*2;
  u16* WCKT = (u16*)p; p += (size_t)(NH*KK9)*AHS*2;
  u16* QS   = (u16*)p; p += (size_t)MTOT*AHS*2;
  u16* KB   = (u16*)p; p += (size_t)MTOT*AHS*2;
  u16* COB  = (u16*)p; p += (size_t)MTOT*AHS*2;
  u16* KCB  = (u16*)p; p += (size_t)MTOT*AHS*2;
  u16* VT   = (u16*)p; p += (size_t)MTOT*AHS*2;
  float* CKP = (float*)p; p += (size_t)MTOT*(NH*KK9)*4;
  float* M8  = (float*)p; p += (size_t)MTOT*4;

  // attn partials alias buffers dead after k_gemm5:
  unsigned* OPb32 = (unsigned*)XBF;  // 4 * (MTOT/2) * AHS * 4B = 25.2MB == XBF+DWBF region
  float* LS = (float*)WTQ;           // 4 * MTOT * NH * 4B = 786KB < WTQ+WTK (dead after gemm5)

  dim3 tb(32,8);
  k_transpose_cast6<<<dim3(24,12,6),tb,0,stream>>>(Wq, Wk, Wv, Wco, pw, Wck,
                                                   WTQ, WTK, WTV, WTCO, WTPW, WCKT);

  k_prep_x<<<MTOT,192,0,stream>>>(X, dwk, amask, XBF, DWBF, M8);

  k_gemm5<<<dim3(64,3,5),256,0,stream>>>(XBF, DWBF, WTQ, WTK, WTV, WTCO, WTPW,
                                         bq, bk, bv, bco, cb,
                                         QS, KB, VT, COB, KCB);

  k_ckgemm<<<256,256,0,stream>>>(QS, KCB, WCKT, bck, CKP);
  k_attn<<<3072,256,0,stream>>>(QS, KB, VT, M8, OPb32, LS);
  k_convout<<<2048,384,0,stream>>>(COB, CKP, OPb32, LS, hmask, out);
}

// Round 13
// 155.563 us; speedup vs baseline: 1.5890x; 1.0192x over previous
//
#include <hip/hip_runtime.h>
#include <hip/hip_bf16.h>
#include <stdint.h>

typedef unsigned short u16;
typedef short bf16x8 __attribute__((ext_vector_type(8)));
typedef float f32x4 __attribute__((ext_vector_type(4)));

#define C_IN 768
#define AHS 384
#define NH 6
#define HD 64
#define KK9 9
#define BSEQ 2048
#define MTOT 8192

__device__ __forceinline__ float b2f(u16 u){
  union { unsigned u; float f; } v; v.u = ((unsigned)u) << 16; return v.f;
}
__device__ __forceinline__ u16 f2b(float f){
  union { float f; unsigned u; } v; v.f = f;
  unsigned r = (v.u + 0x7FFFu + ((v.u >> 16) & 1u)) >> 16;
  return (u16)r;
}
__device__ __forceinline__ void gload_lds16(const void* g, void* l){
  __builtin_amdgcn_global_load_lds((const __attribute__((address_space(1))) unsigned int*)g,
                                   (__attribute__((address_space(3))) unsigned int*)l, 16, 0, 0);
}
__device__ __forceinline__ unsigned cvtpk_bf16(float lo, float hi){
  unsigned w;
  asm("v_cvt_pk_bf16_f32 %0, %1, %2" : "=v"(w) : "v"(lo), "v"(hi));
  return w;
}

#define SCL 0.18033688011112042f   // 0.125 * log2(e)
#define INVSCL 5.545177444479562f  // 8 * ln(2)
#define LOG2E 1.4426950408889634f

// ---------------- transpose + cast f32[R][C] -> bf16[C][R], 6 weights fused ----------------
__global__ void k_transpose_cast6(const float* __restrict__ s0, const float* __restrict__ s1,
                                  const float* __restrict__ s2, const float* __restrict__ s3,
                                  const float* __restrict__ s4, const float* __restrict__ s5,
                                  u16* __restrict__ d0, u16* __restrict__ d1, u16* __restrict__ d2,
                                  u16* __restrict__ d3, u16* __restrict__ d4, u16* __restrict__ d5){
  __shared__ float t[32][33];
  int z = blockIdx.z;
  const float* src = (z==0)?s0:(z==1)?s1:(z==2)?s2:(z==3)?s3:(z==4)?s4:s5;
  u16* dst = (z==0)?d0:(z==1)?d1:(z==2)?d2:(z==3)?d3:(z==4)?d4:d5;
  int R = (z<5) ? C_IN : AHS;
  int C = (z<5) ? AHS : (NH*KK9);
  int r0 = blockIdx.x*32, c0 = blockIdx.y*32;
  if (r0 >= R || c0 >= C) return;
  int tx = threadIdx.x, ty = threadIdx.y;
  #pragma unroll
  for (int j=0;j<4;j++){
    int r = r0 + ty + j*8, c = c0 + tx;
    t[ty+j*8][tx] = (r<R && c<C) ? src[(size_t)r*C + c] : 0.f;
  }
  __syncthreads();
  #pragma unroll
  for (int j=0;j<4;j++){
    int c = c0 + ty + j*8, r = r0 + tx;
    if (r<R && c<C) dst[(size_t)c*R + r] = f2b(t[tx][ty+j*8]);
  }
}

// ---------------- X cast + depthwise conv (SAME), plus M8 = amask*log2e ----------------
__global__ __launch_bounds__(192) void k_prep_x(const float* __restrict__ X, const float* __restrict__ dwk,
                          const float* __restrict__ amask,
                          u16* __restrict__ Xbf, u16* __restrict__ DWbf, float* __restrict__ M8){
  int blk = blockIdx.x; int b = blk>>11; int s = blk&2047;
  int c0 = threadIdx.x*4;
  if (threadIdx.x == 0) M8[blk] = amask[blk] * LOG2E;
  size_t base = (size_t)blk*C_IN + c0;
  float4 xc = *(const float4*)(X + base);
  *(ushort4*)(Xbf + base) = make_ushort4(f2b(xc.x), f2b(xc.y), f2b(xc.z), f2b(xc.w));
  float a0=0.f,a1=0.f,a2=0.f,a3=0.f;
  #pragma unroll
  for (int k=0;k<KK9;k++){
    int ss = s + k - 4;
    if ((unsigned)ss < 2048u){
      float4 xv = *(const float4*)(X + ((size_t)((b<<11)+ss)*C_IN + c0));
      float4 wv = *(const float4*)(dwk + k*C_IN + c0);
      a0 += xv.x*wv.x; a1 += xv.y*wv.y; a2 += xv.z*wv.z; a3 += xv.w*wv.w;
    }
  }
  *(ushort4*)(DWbf + base) = make_ushort4(f2b(a0), f2b(a1), f2b(a2), f2b(a3));
}

// ---------------- 5-way fused projection GEMM: [8192,768]x[768,384] ----------------
// z: 0=Q(-> scaled by SCL) 1=K 2=V(-> transposed Vt) 3=CO 4=KeyConv
__global__ __launch_bounds__(256) void k_gemm5(
    const u16* __restrict__ Xbf, const u16* __restrict__ DWbf,
    const u16* __restrict__ WtQ, const u16* __restrict__ WtK, const u16* __restrict__ WtV,
    const u16* __restrict__ WtCO, const u16* __restrict__ WtPW,
    const float* __restrict__ bq, const float* __restrict__ bk_, const float* __restrict__ bv,
    const float* __restrict__ bco, const float* __restrict__ bcv,
    u16* __restrict__ Qo, u16* __restrict__ Ko, u16* __restrict__ Vt,
    u16* __restrict__ COo, u16* __restrict__ KCo)
{
  __shared__ char smem[32768];
  int tid = threadIdx.x, l = tid&63, w = tid>>6;
  int g = l>>4, c = l&15;
  int wr = w>>1, wc = w&1;
  int mt = blockIdx.x, nt = blockIdx.y, z = blockIdx.z;
  const u16* A = (z==4) ? DWbf : Xbf;
  const u16* B = (z==0)?WtQ:(z==1)?WtK:(z==2)?WtV:(z==3)?WtCO:WtPW;
  const float* bias = (z==0)?bq:(z==1)?bk_:(z==2)?bv:(z==3)?bco:bcv;
  float oscale = (z==0) ? SCL : 1.0f;

  char* La = smem; char* Lb = smem + 16384;
  int m0 = mt*128, n0 = nt*128;

  f32x4 zero = {0.f,0.f,0.f,0.f};
  f32x4 acc[4][4];
  #pragma unroll
  for (int i=0;i<4;i++)
    #pragma unroll
    for (int j=0;j<4;j++) acc[i][j] = zero;

  int rr = w*8 + (l>>3);
  int ch = l&7;

  for (int kt=0; kt<12; kt++){
    #pragma unroll
    for (int i=0;i<4;i++){
      int row = i*32 + rr;
      int sc = ch ^ (row&7);
      gload_lds16(A + (size_t)(m0+row)*C_IN + kt*64 + sc*8, La + i*4096 + w*1024);
      gload_lds16(B + (size_t)(n0+row)*C_IN + kt*64 + sc*8, Lb + i*4096 + w*1024);
    }
    __syncthreads();
    bf16x8 af[4][2], bfr[4][2];
    #pragma unroll
    for (int mi=0;mi<4;mi++){
      int row = wr*64 + mi*16 + c;
      #pragma unroll
      for (int kk=0;kk<2;kk++){
        int sw = (kk*4+g) ^ (row&7);
        af[mi][kk] = *(const bf16x8*)(La + row*128 + sw*16);
      }
    }
    #pragma unroll
    for (int ni=0;ni<4;ni++){
      int row = wc*64 + ni*16 + c;
      #pragma unroll
      for (int kk=0;kk<2;kk++){
        int sw = (kk*4+g) ^ (row&7);
        bfr[ni][kk] = *(const bf16x8*)(Lb + row*128 + sw*16);
      }
    }
    #pragma unroll
    for (int kk=0;kk<2;kk++)
      #pragma unroll
      for (int mi=0;mi<4;mi++)
        #pragma unroll
        for (int ni=0;ni<4;ni++)
          acc[mi][ni] = __builtin_amdgcn_mfma_f32_16x16x32_bf16(af[mi][kk], bfr[ni][kk], acc[mi][ni], 0,0,0);
    __syncthreads();
  }

  if (z == 2){
    #pragma unroll
    for (int ni=0;ni<4;ni++){
      int col = n0 + wc*64 + ni*16 + c;
      float bvv = bias[col];
      int hh = col>>6, d = col&63;
      #pragma unroll
      for (int mi=0;mi<4;mi++){
        int rowg = m0 + wr*64 + mi*16 + g*4;
        int bb = rowg>>11, s = rowg&2047;
        ushort4 pk = make_ushort4(f2b(acc[mi][ni][0] + bvv), f2b(acc[mi][ni][1] + bvv),
                                  f2b(acc[mi][ni][2] + bvv), f2b(acc[mi][ni][3] + bvv));
        *(ushort4*)(Vt + ((size_t)((bb*NH+hh)*HD + d))*BSEQ + s) = pk;
      }
    }
  } else {
    u16* O = (z==0)?Qo:(z==1)?Ko:(z==3)?COo:KCo;
    #pragma unroll
    for (int ni=0;ni<4;ni++){
      int col = n0 + wc*64 + ni*16 + c;
      float bvv = bias[col];
      #pragma unroll
      for (int mi=0;mi<4;mi++)
        #pragma unroll
        for (int r=0;r<4;r++){
          int rowg = m0 + wr*64 + mi*16 + g*4 + r;
          O[(size_t)rowg*AHS + col] = f2b((acc[mi][ni][r] + bvv) * oscale);
        }
    }
  }
}

// ---------------- span-kernel GEMM + softmax: CKP[8192][54] ----------------
__global__ __launch_bounds__(256) void k_ckgemm(const u16* __restrict__ QS, const u16* __restrict__ KCb,
    const u16* __restrict__ WckT, const float* __restrict__ bck, float* __restrict__ ckp)
{
  __shared__ char smem[73728];   // W 48K | CA 24K
  int tid = threadIdx.x, l = tid&63, w = tid>>6;
  int g = l>>4, c = l&15;
  int m0 = blockIdx.x * 32;
  char* Wl = smem;
  char* Al = smem + 49152;

  #pragma unroll
  for (int p=0; p<12; p++){
    int cid = p*256 + tid;
    int row = cid/48, chq = cid - row*48;
    int srow = row < 54 ? row : 53;
    int sch = (chq & ~7) | ((chq ^ row) & 7);
    gload_lds16(WckT + (size_t)srow*AHS + sch*8, Wl + p*4096 + w*1024);
  }
  #pragma unroll
  for (int p=0; p<6; p++){
    int cid = p*256 + tid;
    int row = cid/48, chq = cid - row*48;
    bf16x8 qv = *(const bf16x8*)(QS  + (size_t)(m0+row)*AHS + chq*8);
    bf16x8 kv = *(const bf16x8*)(KCb + (size_t)(m0+row)*AHS + chq*8);
    union { unsigned u[4]; bf16x8 v; } uu;
    #pragma unroll
    for (int j=0;j<4;j++){
      float lo = b2f((u16)qv[2*j])   * b2f((u16)kv[2*j])   * INVSCL;
      float hi = b2f((u16)qv[2*j+1]) * b2f((u16)kv[2*j+1]) * INVSCL;
      uu.u[j] = cvtpk_bf16(lo, hi);
    }
    int sch = (chq & ~7) | ((chq ^ row) & 7);
    *(bf16x8*)(Al + row*768 + sch*16) = uu.v;
  }
  __syncthreads();

  f32x4 zero = {0.f,0.f,0.f,0.f};
  f32x4 acc[2] = {zero, zero};
  #pragma unroll
  for (int ks=0; ks<12; ks++){
    bf16x8 af[2], bfr;
    #pragma unroll
    for (int mi=0;mi<2;mi++){
      int row = mi*16 + c;
      int chq = ks*4 + g;
      int sch = (chq & ~7) | ((chq ^ row) & 7);
      af[mi] = *(const bf16x8*)(Al + row*768 + sch*16);
    }
    {
      int row = w*16 + c;
      int chq = ks*4 + g;
      int sch = (chq & ~7) | ((chq ^ row) & 7);
      bfr = *(const bf16x8*)(Wl + row*768 + sch*16);
    }
    acc[0] = __builtin_amdgcn_mfma_f32_16x16x32_bf16(af[0], bfr, acc[0], 0,0,0);
    acc[1] = __builtin_amdgcn_mfma_f32_16x16x32_bf16(af[1], bfr, acc[1], 0,0,0);
  }

  float* LG = (float*)Al;
  __syncthreads();
  int n = w*16 + c;
  float bb = (n < 54) ? bck[n] : 0.f;
  #pragma unroll
  for (int mi=0;mi<2;mi++)
    #pragma unroll
    for (int r=0;r<4;r++){
      int m = mi*16 + g*4 + r;
      LG[m*64 + n] = acc[mi][r] + bb;
    }
  __syncthreads();
  if (tid < 192){
    int row = tid/6, hh = tid - (tid/6)*6;
    float lg9[9];
    float mx = -1e30f;
    #pragma unroll
    for (int j=0;j<9;j++){ lg9[j] = LG[row*64 + hh*9 + j]; mx = fmaxf(mx, lg9[j]); }
    float s = 0.f;
    #pragma unroll
    for (int j=0;j<9;j++){ lg9[j] = __expf(lg9[j]-mx); s += lg9[j]; }
    float inv = 1.f/s;
    #pragma unroll
    for (int j=0;j<9;j++) ckp[(size_t)(m0+row)*(NH*KK9) + hh*9 + j] = lg9[j]*inv;
  }
}

// ---------------- fused tail: dynamic-conv output + attn 4-way k-split combine ----------------
// OPb32: [split][MTOT/2 row-pairs][AHS] u32; each u32 = (bf16 row_even, bf16 row_odd).
__global__ __launch_bounds__(384) void k_convout(const u16* __restrict__ CO, const float* __restrict__ ckp,
                                                 const unsigned* __restrict__ OPb32, const float* __restrict__ LS,
                                                 const float* __restrict__ hmask, float* __restrict__ out)
{
  int tid = threadIdx.x;
  int pos = tid/96, lane96 = tid - pos*96;
  int sIdx = blockIdx.x*4 + pos;
  int b = sIdx>>11, s = sIdx&2047;
  int cc = lane96*4, h = cc>>6;
  __shared__ float ck[4][NH*KK9];
  if (lane96 < NH*KK9) ck[pos][lane96] = ckp[(size_t)sIdx*(NH*KK9) + lane96];
  __syncthreads();
  // conv half -> out[:, 384+cc]
  float a0=0.f,a1=0.f,a2=0.f,a3=0.f;
  #pragma unroll
  for (int k=0;k<KK9;k++){
    int ss = s + k - 4;
    if ((unsigned)ss < 2048u){
      ushort4 v = *(const ushort4*)(CO + ((size_t)((b<<11)+ss)*AHS + cc));
      float wk = ck[pos][h*KK9+k];
      a0 += b2f(v.x)*wk; a1 += b2f(v.y)*wk; a2 += b2f(v.z)*wk; a3 += b2f(v.w)*wk;
    }
  }
  *(float4*)(out + (size_t)sIdx*(2*AHS) + AHS + cc) = make_float4(a0,a1,a2,a3);
  // attn half (combine 4 k-split quarters) -> out[:, cc]
  int pr = sIdx>>1, sub = sIdx&1;
  float o0=0.f,o1=0.f,o2=0.f,o3=0.f, lsum=0.f;
  #pragma unroll
  for (int sp=0; sp<4; sp++){
    uint4 w4 = *(const uint4*)(OPb32 + ((size_t)(sp*(MTOT/2) + pr))*AHS + cc);
    o0 += b2f((u16)(sub ? (w4.x>>16) : (w4.x&0xFFFF)));
    o1 += b2f((u16)(sub ? (w4.y>>16) : (w4.y&0xFFFF)));
    o2 += b2f((u16)(sub ? (w4.z>>16) : (w4.z&0xFFFF)));
    o3 += b2f((u16)(sub ? (w4.w>>16) : (w4.w&0xFFFF)));
    lsum += LS[((size_t)(sp*MTOT + sIdx))*NH + h];
  }
  float sc = hmask[h] / lsum;
  *(float4*)(out + (size_t)sIdx*(2*AHS) + cc) = make_float4(o0*sc, o1*sc, o2*sc, o3*sc);
}

// ---------------- flash attention (k-split x4, KVBLK=64, 32q/wave) ----------------
// 1536 blocks: (bh, qt, quarter). 4 waves x 32 q-rows = 128 q/block; 8 KV-iters of 64.
// 32KB LDS + VGPR~100 -> ~5 blocks/CU resident (vs R9's 3). Halved LDS reads per q-row.
// Row-pair-packed bf16 partials (64B segments). Plain launch_bounds (NO ,4 -> no spill).
#define AITER(T, P) do { \
    if ((T) < 7){ \
      int tn = (T)+1; \
      _Pragma("unroll") \
      for (int i=0;i<2;i++){ \
        int row = i*32 + rr; int sc = ch ^ (row&7); \
        gload_lds16(Kbase + (size_t)(tn*64 + row)*AHS + sc*8, Kls + ((P)^1)*8192 + i*4096 + w*1024); \
        gload_lds16(Vbase + (size_t)row*BSEQ + tn*64 + sc*8,  Vls + ((P)^1)*8192 + i*4096 + w*1024); \
      } \
    } \
    bf16x8 kf[4][2]; \
    _Pragma("unroll") \
    for (int ka=0;ka<4;ka++){ \
      int row = ka*16 + c; \
      _Pragma("unroll") \
      for (int kk=0;kk<2;kk++){ \
        int swz = (kk*4+g) ^ (row&7); \
        kf[ka][kk] = *(const bf16x8*)(Kls + (P)*8192 + row*128 + swz*16); \
      } \
    } \
    float4 mk[4]; \
    _Pragma("unroll") \
    for (int ka=0;ka<4;ka++) mk[ka] = *(const float4*)(mrow + (T)*64 + ka*16 + g*4); \
    unsigned pkw[2][4][2]; \
    _Pragma("unroll") \
    for (int qh=0;qh<2;qh++){ \
      f32x4 s4[4]; \
      _Pragma("unroll") \
      for (int ka=0;ka<4;ka++){ s4[ka][0]=mk[ka].x; s4[ka][1]=mk[ka].y; s4[ka][2]=mk[ka].z; s4[ka][3]=mk[ka].w; } \
      __builtin_amdgcn_s_setprio(1); \
      _Pragma("unroll") \
      for (int ka=0;ka<4;ka++){ \
        s4[ka] = __builtin_amdgcn_mfma_f32_16x16x32_bf16(kf[ka][0], aq[qh][0], s4[ka], 0,0,0); \
        s4[ka] = __builtin_amdgcn_mfma_f32_16x16x32_bf16(kf[ka][1], aq[qh][1], s4[ka], 0,0,0); \
      } \
      __builtin_amdgcn_s_setprio(0); \
      _Pragma("unroll") \
      for (int ka=0;ka<4;ka++){ \
        float p0 = exp2f(s4[ka][0]); \
        float p1 = exp2f(s4[ka][1]); \
        float p2 = exp2f(s4[ka][2]); \
        float p3 = exp2f(s4[ka][3]); \
        pkw[qh][ka][0] = cvtpk_bf16(p0, p1); \
        pkw[qh][ka][1] = cvtpk_bf16(p2, p3); \
      } \
    } \
    bf16x8 pa[2][2]; \
    _Pragma("unroll") \
    for (int qh=0;qh<2;qh++){ \
      _Pragma("unroll") \
      for (int kk=0;kk<2;kk++){ \
        unsigned e0 = pkw[qh][2*kk][0],   e1 = pkw[qh][2*kk][1]; \
        unsigned o0 = pkw[qh][2*kk+1][0], o1 = pkw[qh][2*kk+1][1]; \
        asm volatile("v_permlane32_swap_b32 %0, %1" : "+v"(e0), "+v"(o0)); \
        asm volatile("v_permlane16_swap_b32 %0, %1" : "+v"(e0), "+v"(o0)); \
        asm volatile("v_permlane32_swap_b32 %0, %1" : "+v"(e1), "+v"(o1)); \
        asm volatile("v_permlane16_swap_b32 %0, %1" : "+v"(e1), "+v"(o1)); \
        union { unsigned u[4]; bf16x8 v; } uu; \
        uu.u[0] = e0; uu.u[1] = e1; uu.u[2] = o0; uu.u[3] = o1; \
        pa[qh][kk] = uu.v; \
      } \
    } \
    bf16x8 vf[4][2]; \
    _Pragma("unroll") \
    for (int di=0;di<4;di++){ \
      int row = di*16 + c; \
      _Pragma("unroll") \
      for (int kk=0;kk<2;kk++){ \
        int swz = (kk*4+g) ^ (row&7); \
        vf[di][kk] = *(const bf16x8*)(Vls + (P)*8192 + row*128 + swz*16); \
      } \
    } \
    __builtin_amdgcn_s_setprio(1); \
    _Pragma("unroll") \
    for (int kk=0;kk<2;kk++){ \
      _Pragma("unroll") \
      for (int qh=0;qh<2;qh++){ \
        _Pragma("unroll") \
        for (int di=0;di<4;di++) \
          o[qh][di] = __builtin_amdgcn_mfma_f32_16x16x32_bf16(pa[qh][kk], vf[di][kk], o[qh][di], 0,0,0); \
        os[qh] = __builtin_amdgcn_mfma_f32_16x16x32_bf16(pa[qh][kk], ONES, os[qh], 0,0,0); \
      } \
    } \
    __builtin_amdgcn_s_setprio(0); \
    __syncthreads(); \
  } while(0)

__global__ __launch_bounds__(256) void k_attn(const u16* __restrict__ QS, const u16* __restrict__ Kb,
    const u16* __restrict__ Vt, const float* __restrict__ M8,
    unsigned* __restrict__ OPb32, float* __restrict__ LS)
{
  __shared__ char smem[32768]; // K dbuf 16K | V dbuf 16K
  int tid = threadIdx.x, l = tid&63, w = tid>>6;
  int g = l>>4, c = l&15;
  // bijective XCD swizzle over 1536 blocks: 192/XCD = 3 bh per XCD
  int n = blockIdx.x;
  int sw = (n & 7) * 192 + (n >> 3);
  int bh = sw >> 6, rem = sw & 63;
  int qt = rem >> 2, qr = rem & 3;
  int b = bh/NH, h = bh - b*NH;

  char* Kls = smem;
  char* Vls = smem + 16384;

  int q0 = qt*128 + w*32;
  bf16x8 aq[2][2];
  #pragma unroll
  for (int qh=0;qh<2;qh++)
    #pragma unroll
    for (int kk=0;kk<2;kk++)
      aq[qh][kk] = *(const bf16x8*)(QS + (size_t)(b*BSEQ + q0 + qh*16 + c)*AHS + h*HD + kk*32 + g*8);

  const bf16x8 ONES = {(short)0x3F80,(short)0x3F80,(short)0x3F80,(short)0x3F80,
                       (short)0x3F80,(short)0x3F80,(short)0x3F80,(short)0x3F80};

  f32x4 o[2][4];
  #pragma unroll
  for (int i=0;i<2;i++)
    #pragma unroll
    for (int j=0;j<4;j++) o[i][j] = f32x4{0.f,0.f,0.f,0.f};
  f32x4 os[2] = {{0.f,0.f,0.f,0.f},{0.f,0.f,0.f,0.f}};

  int rr = w*8 + (l>>3), ch = l&7;
  const u16* Kbase = Kb + ((size_t)b*BSEQ + qr*512)*AHS + h*HD;
  const u16* Vbase = Vt + (size_t)bh*HD*BSEQ + qr*512;
  const float* mrow = M8 + b*BSEQ + qr*512;

  #pragma unroll
  for (int i=0;i<2;i++){
    int row = i*32 + rr; int sc = ch ^ (row&7);
    gload_lds16(Kbase + (size_t)row*AHS + sc*8, Kls + i*4096 + w*1024);
    gload_lds16(Vbase + (size_t)row*BSEQ + sc*8, Vls + i*4096 + w*1024);
  }
  __syncthreads();

  for (int tt=0; tt<4; tt++){
    AITER(2*tt, 0);
    AITER(2*tt+1, 1);
  }

  // packed bf16 partials: rows (r, r+1) -> one u32 per (qh, di, lane c)
  #pragma unroll
  for (int qh=0;qh<2;qh++)
    #pragma unroll
    for (int r=0;r<4;r+=2){
      int rowq = q0 + qh*16 + g*4 + r;
      size_t rp = (size_t)(qr*(MTOT/2)) + ((size_t)(b*BSEQ + rowq) >> 1);
      if (c == 0){
        LS[((size_t)(qr*MTOT + b*BSEQ + rowq))*NH + h]     = os[qh][r];
        LS[((size_t)(qr*MTOT + b*BSEQ + rowq + 1))*NH + h] = os[qh][r+1];
      }
      #pragma unroll
      for (int di=0;di<4;di++)
        OPb32[rp*AHS + h*HD + di*16 + c] = cvtpk_bf16(o[qh][di][r], o[qh][di][r+1]);
    }
}

extern "C" void kernel_launch(void* const* d_in, const int* in_sizes, int n_in,
                              void* d_out, int out_size, void* d_ws, size_t ws_size,
                              hipStream_t stream) {
  (void)in_sizes; (void)n_in; (void)out_size; (void)ws_size;
  const float* X     = (const float*)d_in[0];
  const float* amask = (const float*)d_in[1];
  const float* hmask = (const float*)d_in[2];
  const float* Wq  = (const float*)d_in[3];
  const float* bq  = (const float*)d_in[4];
  const float* Wk  = (const float*)d_in[5];
  const float* bk  = (const float*)d_in[6];
  const float* Wv  = (const float*)d_in[7];
  const float* bv  = (const float*)d_in[8];
  const float* dwk = (const float*)d_in[9];
  const float* pw  = (const float*)d_in[10];
  const float* cb  = (const float*)d_in[11];
  const float* Wck = (const float*)d_in[12];
  const float* bck = (const float*)d_in[13];
  const float* Wco = (const float*)d_in[14];
  const float* bco = (const float*)d_in[15];
  float* out = (float*)d_out;

  char* p = (char*)d_ws;
  u16* XBF  = (u16*)p; p += (size_t)MTOT*C_IN*2;
  u16* DWBF = (u16*)p; p += (size_t)MTOT*C_IN*2;
  u16* WTQ  = (u16*)p; p += (size_t)C_IN*AHS*2;
  u16* WTK  = (u16*)p; p += (size_t)C_IN*AHS*2;
  u16* WTV  = (u16*)p; p += (size_t)C_IN*AHS*2;
  u16* WTCO = (u16*)p; p += (size_t)C_IN*AHS*2;
  u16* WTPW = (u16*)p; p += (size_t)C_IN*AHS*2;
  u16* WCKT = (u16*)p; p += (size_t)(NH*KK9)*AHS*2;
  u16* QS   = (u16*)p; p += (size_t)MTOT*AHS*2;
  u16* KB   = (u16*)p; p += (size_t)MTOT*AHS*2;
  u16* COB  = (u16*)p; p += (size_t)MTOT*AHS*2;
  u16* KCB  = (u16*)p; p += (size_t)MTOT*AHS*2;
  u16* VT   = (u16*)p; p += (size_t)MTOT*AHS*2;
  float* CKP = (float*)p; p += (size_t)MTOT*(NH*KK9)*4;
  float* M8  = (float*)p; p += (size_t)MTOT*4;

  // attn partials alias buffers dead after k_gemm5:
  unsigned* OPb32 = (unsigned*)XBF;  // 4 * (MTOT/2) * AHS * 4B = 25.2MB == XBF+DWBF region
  float* LS = (float*)WTQ;           // 4 * MTOT * NH * 4B = 786KB < WTQ+WTK (dead after gemm5)

  dim3 tb(32,8);
  k_transpose_cast6<<<dim3(24,12,6),tb,0,stream>>>(Wq, Wk, Wv, Wco, pw, Wck,
                                                   WTQ, WTK, WTV, WTCO, WTPW, WCKT);

  k_prep_x<<<MTOT,192,0,stream>>>(X, dwk, amask, XBF, DWBF, M8);

  k_gemm5<<<dim3(64,3,5),256,0,stream>>>(XBF, DWBF, WTQ, WTK, WTV, WTCO, WTPW,
                                         bq, bk, bv, bco, cb,
                                         QS, KB, VT, COB, KCB);

  k_ckgemm<<<256,256,0,stream>>>(QS, KCB, WCKT, bck, CKP);
  k_attn<<<1536,256,0,stream>>>(QS, KB, VT, M8, OPb32, LS);
  k_convout<<<2048,384,0,stream>>>(COB, CKP, OPb32, LS, hmask, out);
}

// Round 14
// 154.388 us; speedup vs baseline: 1.6011x; 1.0076x over previous
//
#include <hip/hip_runtime.h>
#include <hip/hip_bf16.h>
#include <stdint.h>

typedef unsigned short u16;
typedef short bf16x8 __attribute__((ext_vector_type(8)));
typedef float f32x4 __attribute__((ext_vector_type(4)));

#define C_IN 768
#define AHS 384
#define NH 6
#define HD 64
#define KK9 9
#define BSEQ 2048
#define MTOT 8192

__device__ __forceinline__ float b2f(u16 u){
  union { unsigned u; float f; } v; v.u = ((unsigned)u) << 16; return v.f;
}
__device__ __forceinline__ u16 f2b(float f){
  union { float f; unsigned u; } v; v.f = f;
  unsigned r = (v.u + 0x7FFFu + ((v.u >> 16) & 1u)) >> 16;
  return (u16)r;
}
__device__ __forceinline__ void gload_lds16(const void* g, void* l){
  __builtin_amdgcn_global_load_lds((const __attribute__((address_space(1))) unsigned int*)g,
                                   (__attribute__((address_space(3))) unsigned int*)l, 16, 0, 0);
}
__device__ __forceinline__ unsigned cvtpk_bf16(float lo, float hi){
  unsigned w;
  asm("v_cvt_pk_bf16_f32 %0, %1, %2" : "=v"(w) : "v"(lo), "v"(hi));
  return w;
}

#define SCL 0.18033688011112042f   // 0.125 * log2(e)
#define INVSCL 5.545177444479562f  // 8 * ln(2)
#define LOG2E 1.4426950408889634f

// ---------------- transpose + cast f32[R][C] -> bf16[C][R], 6 weights fused ----------------
__global__ void k_transpose_cast6(const float* __restrict__ s0, const float* __restrict__ s1,
                                  const float* __restrict__ s2, const float* __restrict__ s3,
                                  const float* __restrict__ s4, const float* __restrict__ s5,
                                  u16* __restrict__ d0, u16* __restrict__ d1, u16* __restrict__ d2,
                                  u16* __restrict__ d3, u16* __restrict__ d4, u16* __restrict__ d5){
  __shared__ float t[32][33];
  int z = blockIdx.z;
  const float* src = (z==0)?s0:(z==1)?s1:(z==2)?s2:(z==3)?s3:(z==4)?s4:s5;
  u16* dst = (z==0)?d0:(z==1)?d1:(z==2)?d2:(z==3)?d3:(z==4)?d4:d5;
  int R = (z<5) ? C_IN : AHS;
  int C = (z<5) ? AHS : (NH*KK9);
  int r0 = blockIdx.x*32, c0 = blockIdx.y*32;
  if (r0 >= R || c0 >= C) return;
  int tx = threadIdx.x, ty = threadIdx.y;
  #pragma unroll
  for (int j=0;j<4;j++){
    int r = r0 + ty + j*8, c = c0 + tx;
    t[ty+j*8][tx] = (r<R && c<C) ? src[(size_t)r*C + c] : 0.f;
  }
  __syncthreads();
  #pragma unroll
  for (int j=0;j<4;j++){
    int c = c0 + ty + j*8, r = r0 + tx;
    if (r<R && c<C) dst[(size_t)c*R + r] = f2b(t[tx][ty+j*8]);
  }
}

// ---------------- X cast + depthwise conv (SAME), plus M8 = amask*log2e ----------------
__global__ __launch_bounds__(192) void k_prep_x(const float* __restrict__ X, const float* __restrict__ dwk,
                          const float* __restrict__ amask,
                          u16* __restrict__ Xbf, u16* __restrict__ DWbf, float* __restrict__ M8){
  int blk = blockIdx.x; int b = blk>>11; int s = blk&2047;
  int c0 = threadIdx.x*4;
  if (threadIdx.x == 0) M8[blk] = amask[blk] * LOG2E;
  size_t base = (size_t)blk*C_IN + c0;
  float4 xc = *(const float4*)(X + base);
  *(ushort4*)(Xbf + base) = make_ushort4(f2b(xc.x), f2b(xc.y), f2b(xc.z), f2b(xc.w));
  float a0=0.f,a1=0.f,a2=0.f,a3=0.f;
  #pragma unroll
  for (int k=0;k<KK9;k++){
    int ss = s + k - 4;
    if ((unsigned)ss < 2048u){
      float4 xv = *(const float4*)(X + ((size_t)((b<<11)+ss)*C_IN + c0));
      float4 wv = *(const float4*)(dwk + k*C_IN + c0);
      a0 += xv.x*wv.x; a1 += xv.y*wv.y; a2 += xv.z*wv.z; a3 += xv.w*wv.w;
    }
  }
  *(ushort4*)(DWbf + base) = make_ushort4(f2b(a0), f2b(a1), f2b(a2), f2b(a3));
}

// ---------------- 5-way fused projection GEMM: [8192,768]x[768,384] ----------------
// z: 0=Q(-> scaled by SCL) 1=K 2=V(-> transposed Vt via LDS-bounce epilogue) 3=CO 4=KeyConv
__global__ __launch_bounds__(256) void k_gemm5(
    const u16* __restrict__ Xbf, const u16* __restrict__ DWbf,
    const u16* __restrict__ WtQ, const u16* __restrict__ WtK, const u16* __restrict__ WtV,
    const u16* __restrict__ WtCO, const u16* __restrict__ WtPW,
    const float* __restrict__ bq, const float* __restrict__ bk_, const float* __restrict__ bv,
    const float* __restrict__ bco, const float* __restrict__ bcv,
    u16* __restrict__ Qo, u16* __restrict__ Ko, u16* __restrict__ Vt,
    u16* __restrict__ COo, u16* __restrict__ KCo)
{
  __shared__ char smem[34816];   // staging 32K; z==2 epilogue reuses as [128 col][272B]
  int tid = threadIdx.x, l = tid&63, w = tid>>6;
  int g = l>>4, c = l&15;
  int wr = w>>1, wc = w&1;
  int mt = blockIdx.x, nt = blockIdx.y, z = blockIdx.z;
  const u16* A = (z==4) ? DWbf : Xbf;
  const u16* B = (z==0)?WtQ:(z==1)?WtK:(z==2)?WtV:(z==3)?WtCO:WtPW;
  const float* bias = (z==0)?bq:(z==1)?bk_:(z==2)?bv:(z==3)?bco:bcv;
  float oscale = (z==0) ? SCL : 1.0f;

  char* La = smem; char* Lb = smem + 16384;
  int m0 = mt*128, n0 = nt*128;

  f32x4 zero = {0.f,0.f,0.f,0.f};
  f32x4 acc[4][4];
  #pragma unroll
  for (int i=0;i<4;i++)
    #pragma unroll
    for (int j=0;j<4;j++) acc[i][j] = zero;

  int rr = w*8 + (l>>3);
  int ch = l&7;

  for (int kt=0; kt<12; kt++){
    #pragma unroll
    for (int i=0;i<4;i++){
      int row = i*32 + rr;
      int sc = ch ^ (row&7);
      gload_lds16(A + (size_t)(m0+row)*C_IN + kt*64 + sc*8, La + i*4096 + w*1024);
      gload_lds16(B + (size_t)(n0+row)*C_IN + kt*64 + sc*8, Lb + i*4096 + w*1024);
    }
    __syncthreads();
    bf16x8 af[4][2], bfr[4][2];
    #pragma unroll
    for (int mi=0;mi<4;mi++){
      int row = wr*64 + mi*16 + c;
      #pragma unroll
      for (int kk=0;kk<2;kk++){
        int sw = (kk*4+g) ^ (row&7);
        af[mi][kk] = *(const bf16x8*)(La + row*128 + sw*16);
      }
    }
    #pragma unroll
    for (int ni=0;ni<4;ni++){
      int row = wc*64 + ni*16 + c;
      #pragma unroll
      for (int kk=0;kk<2;kk++){
        int sw = (kk*4+g) ^ (row&7);
        bfr[ni][kk] = *(const bf16x8*)(Lb + row*128 + sw*16);
      }
    }
    #pragma unroll
    for (int kk=0;kk<2;kk++)
      #pragma unroll
      for (int mi=0;mi<4;mi++)
        #pragma unroll
        for (int ni=0;ni<4;ni++)
          acc[mi][ni] = __builtin_amdgcn_mfma_f32_16x16x32_bf16(af[mi][kk], bfr[ni][kk], acc[mi][ni], 0,0,0);
    __syncthreads();
  }

  if (z == 2){
    // ---- LDS-bounce epilogue: avoid 8B-scattered Vt stores ----
    // LDS layout: col_local (0..127) x 272B; element (col, s) at byte
    //   col*272 + (((s>>3) ^ (col&7)) & 15)*16 + (s&7)*2
    // write: each thread packs 4 consecutive s (one ushort4 = 8B) per (mi,ni)
    #pragma unroll
    for (int ni=0;ni<4;ni++){
      int col = wc*64 + ni*16 + c;
      float bvv = bias[n0 + col];
      #pragma unroll
      for (int mi=0;mi<4;mi++){
        int s0 = wr*64 + mi*16 + g*4;
        ushort4 pk = make_ushort4(f2b(acc[mi][ni][0] + bvv), f2b(acc[mi][ni][1] + bvv),
                                  f2b(acc[mi][ni][2] + bvv), f2b(acc[mi][ni][3] + bvv));
        int chunk = ((s0>>3) ^ (col&7)) & 15;
        *(ushort4*)(smem + col*272 + chunk*16 + (s0&4)*2) = pk;
      }
    }
    __syncthreads();
    // read back: per pass, 16 cols; wave covers 4 cols x 16 s-chunks -> 256B runs
    int bb = m0 >> 11;
    #pragma unroll
    for (int p=0; p<8; p++){
      int col = p*16 + (tid>>4);        // 0..127
      int sch = tid & 15;               // s chunk (8 elements)
      int chunk = (sch ^ (col&7)) & 15;
      bf16x8 v = *(const bf16x8*)(smem + col*272 + chunk*16);
      int colg = n0 + col;
      int hh = colg>>6, d = colg&63;
      int sg = (m0 & 2047) + sch*8;
      *(bf16x8*)(Vt + ((size_t)((bb*NH+hh)*HD + d))*BSEQ + sg) = v;
    }
  } else {
    u16* O = (z==0)?Qo:(z==1)?Ko:(z==3)?COo:KCo;
    #pragma unroll
    for (int ni=0;ni<4;ni++){
      int col = n0 + wc*64 + ni*16 + c;
      float bvv = bias[col];
      #pragma unroll
      for (int mi=0;mi<4;mi++)
        #pragma unroll
        for (int r=0;r<4;r++){
          int rowg = m0 + wr*64 + mi*16 + g*4 + r;
          O[(size_t)rowg*AHS + col] = f2b((acc[mi][ni][r] + bvv) * oscale);
        }
    }
  }
}

// ---------------- span-kernel GEMM + softmax: CKP[8192][54] ----------------
__global__ __launch_bounds__(256) void k_ckgemm(const u16* __restrict__ QS, const u16* __restrict__ KCb,
    const u16* __restrict__ WckT, const float* __restrict__ bck, float* __restrict__ ckp)
{
  __shared__ char smem[73728];   // W 48K | CA 24K
  int tid = threadIdx.x, l = tid&63, w = tid>>6;
  int g = l>>4, c = l&15;
  int m0 = blockIdx.x * 32;
  char* Wl = smem;
  char* Al = smem + 49152;

  #pragma unroll
  for (int p=0; p<12; p++){
    int cid = p*256 + tid;
    int row = cid/48, chq = cid - row*48;
    int srow = row < 54 ? row : 53;
    int sch = (chq & ~7) | ((chq ^ row) & 7);
    gload_lds16(WckT + (size_t)srow*AHS + sch*8, Wl + p*4096 + w*1024);
  }
  #pragma unroll
  for (int p=0; p<6; p++){
    int cid = p*256 + tid;
    int row = cid/48, chq = cid - row*48;
    bf16x8 qv = *(const bf16x8*)(QS  + (size_t)(m0+row)*AHS + chq*8);
    bf16x8 kv = *(const bf16x8*)(KCb + (size_t)(m0+row)*AHS + chq*8);
    union { unsigned u[4]; bf16x8 v; } uu;
    #pragma unroll
    for (int j=0;j<4;j++){
      float lo = b2f((u16)qv[2*j])   * b2f((u16)kv[2*j])   * INVSCL;
      float hi = b2f((u16)qv[2*j+1]) * b2f((u16)kv[2*j+1]) * INVSCL;
      uu.u[j] = cvtpk_bf16(lo, hi);
    }
    int sch = (chq & ~7) | ((chq ^ row) & 7);
    *(bf16x8*)(Al + row*768 + sch*16) = uu.v;
  }
  __syncthreads();

  f32x4 zero = {0.f,0.f,0.f,0.f};
  f32x4 acc[2] = {zero, zero};
  #pragma unroll
  for (int ks=0; ks<12; ks++){
    bf16x8 af[2], bfr;
    #pragma unroll
    for (int mi=0;mi<2;mi++){
      int row = mi*16 + c;
      int chq = ks*4 + g;
      int sch = (chq & ~7) | ((chq ^ row) & 7);
      af[mi] = *(const bf16x8*)(Al + row*768 + sch*16);
    }
    {
      int row = w*16 + c;
      int chq = ks*4 + g;
      int sch = (chq & ~7) | ((chq ^ row) & 7);
      bfr = *(const bf16x8*)(Wl + row*768 + sch*16);
    }
    acc[0] = __builtin_amdgcn_mfma_f32_16x16x32_bf16(af[0], bfr, acc[0], 0,0,0);
    acc[1] = __builtin_amdgcn_mfma_f32_16x16x32_bf16(af[1], bfr, acc[1], 0,0,0);
  }

  float* LG = (float*)Al;
  __syncthreads();
  int n = w*16 + c;
  float bb = (n < 54) ? bck[n] : 0.f;
  #pragma unroll
  for (int mi=0;mi<2;mi++)
    #pragma unroll
    for (int r=0;r<4;r++){
      int m = mi*16 + g*4 + r;
      LG[m*64 + n] = acc[mi][r] + bb;
    }
  __syncthreads();
  if (tid < 192){
    int row = tid/6, hh = tid - (tid/6)*6;
    float lg9[9];
    float mx = -1e30f;
    #pragma unroll
    for (int j=0;j<9;j++){ lg9[j] = LG[row*64 + hh*9 + j]; mx = fmaxf(mx, lg9[j]); }
    float s = 0.f;
    #pragma unroll
    for (int j=0;j<9;j++){ lg9[j] = __expf(lg9[j]-mx); s += lg9[j]; }
    float inv = 1.f/s;
    #pragma unroll
    for (int j=0;j<9;j++) ckp[(size_t)(m0+row)*(NH*KK9) + hh*9 + j] = lg9[j]*inv;
  }
}

// ---------------- fused tail: dynamic-conv output + attn 4-way k-split combine ----------------
// OPb32: [split][MTOT/2 row-pairs][AHS] u32; each u32 = (bf16 row_even, bf16 row_odd).
__global__ __launch_bounds__(384) void k_convout(const u16* __restrict__ CO, const float* __restrict__ ckp,
                                                 const unsigned* __restrict__ OPb32, const float* __restrict__ LS,
                                                 const float* __restrict__ hmask, float* __restrict__ out)
{
  int tid = threadIdx.x;
  int pos = tid/96, lane96 = tid - pos*96;
  int sIdx = blockIdx.x*4 + pos;
  int b = sIdx>>11, s = sIdx&2047;
  int cc = lane96*4, h = cc>>6;
  __shared__ float ck[4][NH*KK9];
  if (lane96 < NH*KK9) ck[pos][lane96] = ckp[(size_t)sIdx*(NH*KK9) + lane96];
  __syncthreads();
  // conv half -> out[:, 384+cc]
  float a0=0.f,a1=0.f,a2=0.f,a3=0.f;
  #pragma unroll
  for (int k=0;k<KK9;k++){
    int ss = s + k - 4;
    if ((unsigned)ss < 2048u){
      ushort4 v = *(const ushort4*)(CO + ((size_t)((b<<11)+ss)*AHS + cc));
      float wk = ck[pos][h*KK9+k];
      a0 += b2f(v.x)*wk; a1 += b2f(v.y)*wk; a2 += b2f(v.z)*wk; a3 += b2f(v.w)*wk;
    }
  }
  *(float4*)(out + (size_t)sIdx*(2*AHS) + AHS + cc) = make_float4(a0,a1,a2,a3);
  // attn half (combine 4 k-split quarters) -> out[:, cc]
  int pr = sIdx>>1, sub = sIdx&1;
  float o0=0.f,o1=0.f,o2=0.f,o3=0.f, lsum=0.f;
  #pragma unroll
  for (int sp=0; sp<4; sp++){
    uint4 w4 = *(const uint4*)(OPb32 + ((size_t)(sp*(MTOT/2) + pr))*AHS + cc);
    o0 += b2f((u16)(sub ? (w4.x>>16) : (w4.x&0xFFFF)));
    o1 += b2f((u16)(sub ? (w4.y>>16) : (w4.y&0xFFFF)));
    o2 += b2f((u16)(sub ? (w4.z>>16) : (w4.z&0xFFFF)));
    o3 += b2f((u16)(sub ? (w4.w>>16) : (w4.w&0xFFFF)));
    lsum += LS[((size_t)(sp*MTOT + sIdx))*NH + h];
  }
  float sc = hmask[h] / lsum;
  *(float4*)(out + (size_t)sIdx*(2*AHS) + cc) = make_float4(o0*sc, o1*sc, o2*sc, o3*sc);
}

// ---------------- flash attention (k-split x4, KVBLK=64, 32q/wave) ----------------
// 1536 blocks: (bh, qt, quarter). 4 waves x 32 q-rows = 128 q/block; 8 KV-iters of 64.
// Row-pair-packed bf16 partials. Plain launch_bounds (NO ,4 -> no spill).
#define AITER(T, P) do { \
    if ((T) < 7){ \
      int tn = (T)+1; \
      _Pragma("unroll") \
      for (int i=0;i<2;i++){ \
        int row = i*32 + rr; int sc = ch ^ (row&7); \
        gload_lds16(Kbase + (size_t)(tn*64 + row)*AHS + sc*8, Kls + ((P)^1)*8192 + i*4096 + w*1024); \
        gload_lds16(Vbase + (size_t)row*BSEQ + tn*64 + sc*8,  Vls + ((P)^1)*8192 + i*4096 + w*1024); \
      } \
    } \
    bf16x8 kf[4][2]; \
    _Pragma("unroll") \
    for (int ka=0;ka<4;ka++){ \
      int row = ka*16 + c; \
      _Pragma("unroll") \
      for (int kk=0;kk<2;kk++){ \
        int swz = (kk*4+g) ^ (row&7); \
        kf[ka][kk] = *(const bf16x8*)(Kls + (P)*8192 + row*128 + swz*16); \
      } \
    } \
    float4 mk[4]; \
    _Pragma("unroll") \
    for (int ka=0;ka<4;ka++) mk[ka] = *(const float4*)(mrow + (T)*64 + ka*16 + g*4); \
    unsigned pkw[2][4][2]; \
    _Pragma("unroll") \
    for (int qh=0;qh<2;qh++){ \
      f32x4 s4[4]; \
      _Pragma("unroll") \
      for (int ka=0;ka<4;ka++){ s4[ka][0]=mk[ka].x; s4[ka][1]=mk[ka].y; s4[ka][2]=mk[ka].z; s4[ka][3]=mk[ka].w; } \
      __builtin_amdgcn_s_setprio(1); \
      _Pragma("unroll") \
      for (int ka=0;ka<4;ka++){ \
        s4[ka] = __builtin_amdgcn_mfma_f32_16x16x32_bf16(kf[ka][0], aq[qh][0], s4[ka], 0,0,0); \
        s4[ka] = __builtin_amdgcn_mfma_f32_16x16x32_bf16(kf[ka][1], aq[qh][1], s4[ka], 0,0,0); \
      } \
      __builtin_amdgcn_s_setprio(0); \
      _Pragma("unroll") \
      for (int ka=0;ka<4;ka++){ \
        float p0 = exp2f(s4[ka][0]); \
        float p1 = exp2f(s4[ka][1]); \
        float p2 = exp2f(s4[ka][2]); \
        float p3 = exp2f(s4[ka][3]); \
        pkw[qh][ka][0] = cvtpk_bf16(p0, p1); \
        pkw[qh][ka][1] = cvtpk_bf16(p2, p3); \
      } \
    } \
    bf16x8 pa[2][2]; \
    _Pragma("unroll") \
    for (int qh=0;qh<2;qh++){ \
      _Pragma("unroll") \
      for (int kk=0;kk<2;kk++){ \
        unsigned e0 = pkw[qh][2*kk][0],   e1 = pkw[qh][2*kk][1]; \
        unsigned o0 = pkw[qh][2*kk+1][0], o1 = pkw[qh][2*kk+1][1]; \
        asm volatile("v_permlane32_swap_b32 %0, %1" : "+v"(e0), "+v"(o0)); \
        asm volatile("v_permlane16_swap_b32 %0, %1" : "+v"(e0), "+v"(o0)); \
        asm volatile("v_permlane32_swap_b32 %0, %1" : "+v"(e1), "+v"(o1)); \
        asm volatile("v_permlane16_swap_b32 %0, %1" : "+v"(e1), "+v"(o1)); \
        union { unsigned u[4]; bf16x8 v; } uu; \
        uu.u[0] = e0; uu.u[1] = e1; uu.u[2] = o0; uu.u[3] = o1; \
        pa[qh][kk] = uu.v; \
      } \
    } \
    bf16x8 vf[4][2]; \
    _Pragma("unroll") \
    for (int di=0;di<4;di++){ \
      int row = di*16 + c; \
      _Pragma("unroll") \
      for (int kk=0;kk<2;kk++){ \
        int swz = (kk*4+g) ^ (row&7); \
        vf[di][kk] = *(const bf16x8*)(Vls + (P)*8192 + row*128 + swz*16); \
      } \
    } \
    __builtin_amdgcn_s_setprio(1); \
    _Pragma("unroll") \
    for (int kk=0;kk<2;kk++){ \
      _Pragma("unroll") \
      for (int qh=0;qh<2;qh++){ \
        _Pragma("unroll") \
        for (int di=0;di<4;di++) \
          o[qh][di] = __builtin_amdgcn_mfma_f32_16x16x32_bf16(pa[qh][kk], vf[di][kk], o[qh][di], 0,0,0); \
        os[qh] = __builtin_amdgcn_mfma_f32_16x16x32_bf16(pa[qh][kk], ONES, os[qh], 0,0,0); \
      } \
    } \
    __builtin_amdgcn_s_setprio(0); \
    __syncthreads(); \
  } while(0)

__global__ __launch_bounds__(256) void k_attn(const u16* __restrict__ QS, const u16* __restrict__ Kb,
    const u16* __restrict__ Vt, const float* __restrict__ M8,
    unsigned* __restrict__ OPb32, float* __restrict__ LS)
{
  __shared__ char smem[32768]; // K dbuf 16K | V dbuf 16K
  int tid = threadIdx.x, l = tid&63, w = tid>>6;
  int g = l>>4, c = l&15;
  // bijective XCD swizzle over 1536 blocks: 192/XCD = 3 bh per XCD
  int n = blockIdx.x;
  int sw = (n & 7) * 192 + (n >> 3);
  int bh = sw >> 6, rem = sw & 63;
  int qt = rem >> 2, qr = rem & 3;
  int b = bh/NH, h = bh - b*NH;

  char* Kls = smem;
  char* Vls = smem + 16384;

  int q0 = qt*128 + w*32;
  bf16x8 aq[2][2];
  #pragma unroll
  for (int qh=0;qh<2;qh++)
    #pragma unroll
    for (int kk=0;kk<2;kk++)
      aq[qh][kk] = *(const bf16x8*)(QS + (size_t)(b*BSEQ + q0 + qh*16 + c)*AHS + h*HD + kk*32 + g*8);

  const bf16x8 ONES = {(short)0x3F80,(short)0x3F80,(short)0x3F80,(short)0x3F80,
                       (short)0x3F80,(short)0x3F80,(short)0x3F80,(short)0x3F80};

  f32x4 o[2][4];
  #pragma unroll
  for (int i=0;i<2;i++)
    #pragma unroll
    for (int j=0;j<4;j++) o[i][j] = f32x4{0.f,0.f,0.f,0.f};
  f32x4 os[2] = {{0.f,0.f,0.f,0.f},{0.f,0.f,0.f,0.f}};

  int rr = w*8 + (l>>3), ch = l&7;
  const u16* Kbase = Kb + ((size_t)b*BSEQ + qr*512)*AHS + h*HD;
  const u16* Vbase = Vt + (size_t)bh*HD*BSEQ + qr*512;
  const float* mrow = M8 + b*BSEQ + qr*512;

  #pragma unroll
  for (int i=0;i<2;i++){
    int row = i*32 + rr; int sc = ch ^ (row&7);
    gload_lds16(Kbase + (size_t)row*AHS + sc*8, Kls + i*4096 + w*1024);
    gload_lds16(Vbase + (size_t)row*BSEQ + sc*8, Vls + i*4096 + w*1024);
  }
  __syncthreads();

  for (int tt=0; tt<4; tt++){
    AITER(2*tt, 0);
    AITER(2*tt+1, 1);
  }

  // packed bf16 partials: rows (r, r+1) -> one u32 per (qh, di, lane c)
  #pragma unroll
  for (int qh=0;qh<2;qh++)
    #pragma unroll
    for (int r=0;r<4;r+=2){
      int rowq = q0 + qh*16 + g*4 + r;
      size_t rp = (size_t)(qr*(MTOT/2)) + ((size_t)(b*BSEQ + rowq) >> 1);
      if (c == 0){
        LS[((size_t)(qr*MTOT + b*BSEQ + rowq))*NH + h]     = os[qh][r];
        LS[((size_t)(qr*MTOT + b*BSEQ + rowq + 1))*NH + h] = os[qh][r+1];
      }
      #pragma unroll
      for (int di=0;di<4;di++)
        OPb32[rp*AHS + h*HD + di*16 + c] = cvtpk_bf16(o[qh][di][r], o[qh][di][r+1]);
    }
}

extern "C" void kernel_launch(void* const* d_in, const int* in_sizes, int n_in,
                              void* d_out, int out_size, void* d_ws, size_t ws_size,
                              hipStream_t stream) {
  (void)in_sizes; (void)n_in; (void)out_size; (void)ws_size;
  const float* X     = (const float*)d_in[0];
  const float* amask = (const float*)d_in[1];
  const float* hmask = (const float*)d_in[2];
  const float* Wq  = (const float*)d_in[3];
  const float* bq  = (const float*)d_in[4];
  const float* Wk  = (const float*)d_in[5];
  const float* bk  = (const float*)d_in[6];
  const float* Wv  = (const float*)d_in[7];
  const float* bv  = (const float*)d_in[8];
  const float* dwk = (const float*)d_in[9];
  const float* pw  = (const float*)d_in[10];
  const float* cb  = (const float*)d_in[11];
  const float* Wck = (const float*)d_in[12];
  const float* bck = (const float*)d_in[13];
  const float* Wco = (const float*)d_in[14];
  const float* bco = (const float*)d_in[15];
  float* out = (float*)d_out;

  char* p = (char*)d_ws;
  u16* XBF  = (u16*)p; p += (size_t)MTOT*C_IN*2;
  u16* DWBF = (u16*)p; p += (size_t)MTOT*C_IN*2;
  u16* WTQ  = (u16*)p; p += (size_t)C_IN*AHS*2;
  u16* WTK  = (u16*)p; p += (size_t)C_IN*AHS*2;
  u16* WTV  = (u16*)p; p += (size_t)C_IN*AHS*2;
  u16* WTCO = (u16*)p; p += (size_t)C_IN*AHS*2;
  u16* WTPW = (u16*)p; p += (size_t)C_IN*AHS*2;
  u16* WCKT = (u16*)p; p += (size_t)(NH*KK9)*AHS*2;
  u16* QS   = (u16*)p; p += (size_t)MTOT*AHS*2;
  u16* KB   = (u16*)p; p += (size_t)MTOT*AHS*2;
  u16* COB  = (u16*)p; p += (size_t)MTOT*AHS*2;
  u16* KCB  = (u16*)p; p += (size_t)MTOT*AHS*2;
  u16* VT   = (u16*)p; p += (size_t)MTOT*AHS*2;
  float* CKP = (float*)p; p += (size_t)MTOT*(NH*KK9)*4;
  float* M8  = (float*)p; p += (size_t)MTOT*4;

  // attn partials alias buffers dead after k_gemm5:
  unsigned* OPb32 = (unsigned*)XBF;  // 4 * (MTOT/2) * AHS * 4B = 25.2MB == XBF+DWBF region
  float* LS = (float*)WTQ;           // 4 * MTOT * NH * 4B = 786KB < WTQ+WTK (dead after gemm5)

  dim3 tb(32,8);
  k_transpose_cast6<<<dim3(24,12,6),tb,0,stream>>>(Wq, Wk, Wv, Wco, pw, Wck,
                                                   WTQ, WTK, WTV, WTCO, WTPW, WCKT);

  k_prep_x<<<MTOT,192,0,stream>>>(X, dwk, amask, XBF, DWBF, M8);

  k_gemm5<<<dim3(64,3,5),256,0,stream>>>(XBF, DWBF, WTQ, WTK, WTV, WTCO, WTPW,
                                         bq, bk, bv, bco, cb,
                                         QS, KB, VT, COB, KCB);

  k_ckgemm<<<256,256,0,stream>>>(QS, KCB, WCKT, bck, CKP);
  k_attn<<<1536,256,0,stream>>>(QS, KB, VT, M8, OPb32, LS);
  k_convout<<<2048,384,0,stream>>>(COB, CKP, OPb32, LS, hmask, out);
}